// Round 3
// baseline (778.197 us; speedup 1.0000x reference)
//
#include <hip/hip_runtime.h>
#include <math.h>

#define VOCN 50257
#define OUTD 512
#define HIDD 64
#define CURD 16
#define BB   32
#define SS   4096
#define NCH  256      // SS / CURD
#define KDIM 80       // HIDD + CURD
#define LNEPS 1e-5f

// workspace layout
#define WS_WHI   41943040                  // combined = [0, 40MB)
#define WS_WLO   (WS_WHI + 96*512*2)
#define WS_FLAGS (WS_WLO + 96*512*2)       // 512 u32: [0]=role tkt [1]=task tkt
#define NRECB    128                       // rec blocks (4 chains each)
#define NOUTB    512
#define NTASKS   4096                      // 131072 rows / 32
#define NSLABS   16                        // 16 chunks per slab
// ready[slab] lives at flags[16 + slab*16]  (64B apart, own cacheline)

// ---------------------------------------------------------------------------
// helpers
// ---------------------------------------------------------------------------
#define DPP_ADD(x, ctrl) \
    ((x) + __int_as_float(__builtin_amdgcn_update_dpp( \
        0, __float_as_int(x), (ctrl), 0xf, 0xf, true)))

__device__ __forceinline__ float row16_sum(float x) {
    x = DPP_ADD(x, 0xB1);   // quad_perm xor1
    x = DPP_ADD(x, 0x4E);   // quad_perm xor2
    x = DPP_ADD(x, 0x141);  // row_half_mirror xor4
    x = DPP_ADD(x, 0x140);  // row_mirror xor8
    return x;
}

__device__ __forceinline__ float wave64_sum(float x) {
    float r = row16_sum(x);
    float a = __int_as_float(__builtin_amdgcn_readlane(__float_as_int(r), 0));
    float b = __int_as_float(__builtin_amdgcn_readlane(__float_as_int(r), 16));
    float c = __int_as_float(__builtin_amdgcn_readlane(__float_as_int(r), 32));
    float d = __int_as_float(__builtin_amdgcn_readlane(__float_as_int(r), 48));
    return (a + b) + (c + d);
}

__device__ __forceinline__ unsigned short f2bf(float x) {
    unsigned u = __float_as_uint(x);
    u += 0x7fffu + ((u >> 16) & 1u);
    return (unsigned short)(u >> 16);
}
__device__ __forceinline__ float bf2f(unsigned short h) {
    return __uint_as_float(((unsigned)h) << 16);
}

typedef __attribute__((ext_vector_type(8))) short bf16x8;
typedef __attribute__((ext_vector_type(4))) float f32x4;

// ---------------------------------------------------------------------------
// Kernel 1: attention (unchanged math) + flag zeroing + Wd packing folded in.
// ---------------------------------------------------------------------------
__global__ __launch_bounds__(256) void attn_kernel(
    const int* __restrict__ x, const float* __restrict__ emb,
    const float* __restrict__ Wq, const float* __restrict__ bq,
    const float* __restrict__ Wk, const float* __restrict__ bk,
    const float* __restrict__ Wv, const float* __restrict__ bv,
    const float* __restrict__ g_lim, const float* __restrict__ b_lim,
    float* __restrict__ combined,
    const float* __restrict__ Wd,
    unsigned short* __restrict__ whi, unsigned short* __restrict__ wlo,
    unsigned int* __restrict__ flags)
{
    if (blockIdx.x == 0) {
        flags[threadIdx.x] = 0u;
        flags[threadIdx.x + 256] = 0u;
    }

    const int wid  = threadIdx.x >> 6;
    const int lane = threadIdx.x & 63;
    const int tile = blockIdx.x * 4 + wid;
    const int t = tile >> 5, b = tile & 31;
    const int i  = lane >> 2;
    const int jg = lane & 3;
    const int j0 = jg * 4;

    __shared__ __align__(16) float ldsT[4][4][16][20];
    float (*R)[20] = ldsT[wid][0];
    float (*Q)[20] = ldsT[wid][1];
    float (*K)[20] = ldsT[wid][2];
    float (*V)[20] = ldsT[wid][3];

    int myid = 0;
    if (lane < 16) myid = x[b * SS + t * CURD + lane];
    const int id_i = __shfl(myid, i, 64);

    float4 r4 = *(const float4*)(emb + (size_t)id_i * CURD + j0);
    *(float4*)&R[i][j0] = r4;

    float rrow[16];
    {
        float4 t0 = *(const float4*)&R[i][0];
        float4 t1 = *(const float4*)&R[i][4];
        float4 t2 = *(const float4*)&R[i][8];
        float4 t3 = *(const float4*)&R[i][12];
        rrow[0]=t0.x; rrow[1]=t0.y; rrow[2]=t0.z;  rrow[3]=t0.w;
        rrow[4]=t1.x; rrow[5]=t1.y; rrow[6]=t1.z;  rrow[7]=t1.w;
        rrow[8]=t2.x; rrow[9]=t2.y; rrow[10]=t2.z; rrow[11]=t2.w;
        rrow[12]=t3.x; rrow[13]=t3.y; rrow[14]=t3.z; rrow[15]=t3.w;
    }

    float4 q4 = *(const float4*)(bq + j0);
    float4 k4 = *(const float4*)(bk + j0);
    float4 v4 = *(const float4*)(bv + j0);
    #pragma unroll
    for (int k = 0; k < 16; ++k) {
        float rv = rrow[k];
        float4 wq4 = *(const float4*)(Wq + k * CURD + j0);
        float4 wk4 = *(const float4*)(Wk + k * CURD + j0);
        float4 wv4 = *(const float4*)(Wv + k * CURD + j0);
        q4.x = fmaf(rv, wq4.x, q4.x); q4.y = fmaf(rv, wq4.y, q4.y);
        q4.z = fmaf(rv, wq4.z, q4.z); q4.w = fmaf(rv, wq4.w, q4.w);
        k4.x = fmaf(rv, wk4.x, k4.x); k4.y = fmaf(rv, wk4.y, k4.y);
        k4.z = fmaf(rv, wk4.z, k4.z); k4.w = fmaf(rv, wk4.w, k4.w);
        v4.x = fmaf(rv, wv4.x, v4.x); v4.y = fmaf(rv, wv4.y, v4.y);
        v4.z = fmaf(rv, wv4.z, v4.z); v4.w = fmaf(rv, wv4.w, v4.w);
    }
    *(float4*)&Q[i][j0] = q4;
    *(float4*)&K[i][j0] = k4;
    *(float4*)&V[i][j0] = v4;

    float qrow[16];
    {
        float4 t0 = *(const float4*)&Q[i][0];
        float4 t1 = *(const float4*)&Q[i][4];
        float4 t2 = *(const float4*)&Q[i][8];
        float4 t3 = *(const float4*)&Q[i][12];
        qrow[0]=t0.x; qrow[1]=t0.y; qrow[2]=t0.z;  qrow[3]=t0.w;
        qrow[4]=t1.x; qrow[5]=t1.y; qrow[6]=t1.z;  qrow[7]=t1.w;
        qrow[8]=t2.x; qrow[9]=t2.y; qrow[10]=t2.z; qrow[11]=t2.w;
        qrow[12]=t3.x; qrow[13]=t3.y; qrow[14]=t3.z; qrow[15]=t3.w;
    }
    float sc[4];
    #pragma unroll
    for (int jj = 0; jj < 4; ++jj) {
        const int row = j0 + jj;
        float4 c0 = *(const float4*)&K[row][0];
        float4 c1 = *(const float4*)&K[row][4];
        float4 c2 = *(const float4*)&K[row][8];
        float4 c3 = *(const float4*)&K[row][12];
        float d0 = qrow[0]*c0.x + qrow[1]*c0.y + qrow[2]*c0.z + qrow[3]*c0.w;
        float d1 = qrow[4]*c1.x + qrow[5]*c1.y + qrow[6]*c1.z + qrow[7]*c1.w;
        float d2 = qrow[8]*c2.x + qrow[9]*c2.y + qrow[10]*c2.z + qrow[11]*c2.w;
        float d3 = qrow[12]*c3.x + qrow[13]*c3.y + qrow[14]*c3.z + qrow[15]*c3.w;
        sc[jj] = ((d0 + d1) + (d2 + d3)) * 0.25f;
    }

    float mx = fmaxf(fmaxf(sc[0], sc[1]), fmaxf(sc[2], sc[3]));
    mx = fmaxf(mx, __shfl_xor(mx, 1));
    mx = fmaxf(mx, __shfl_xor(mx, 2));
    float e0 = expf(sc[0]-mx), e1 = expf(sc[1]-mx),
          e2 = expf(sc[2]-mx), e3 = expf(sc[3]-mx);
    float es = (e0 + e1) + (e2 + e3);
    es += __shfl_xor(es, 1);
    es += __shfl_xor(es, 2);
    float rs = 1.f / es;
    float4 p4 = make_float4(e0*rs, e1*rs, e2*rs, e3*rs);
    *(float4*)&R[i][j0] = p4;

    float prow[16];
    {
        float4 t0 = *(const float4*)&R[i][0];
        float4 t1 = *(const float4*)&R[i][4];
        float4 t2 = *(const float4*)&R[i][8];
        float4 t3 = *(const float4*)&R[i][12];
        prow[0]=t0.x; prow[1]=t0.y; prow[2]=t0.z;  prow[3]=t0.w;
        prow[4]=t1.x; prow[5]=t1.y; prow[6]=t1.z;  prow[7]=t1.w;
        prow[8]=t2.x; prow[9]=t2.y; prow[10]=t2.z; prow[11]=t2.w;
        prow[12]=t3.x; prow[13]=t3.y; prow[14]=t3.z; prow[15]=t3.w;
    }
    float4 w4 = make_float4(0.f, 0.f, 0.f, 0.f);
    #pragma unroll
    for (int k = 0; k < 16; ++k) {
        float4 vk = *(const float4*)&V[k][j0];
        float pv = prow[k];
        w4.x = fmaf(pv, vk.x, w4.x); w4.y = fmaf(pv, vk.y, w4.y);
        w4.z = fmaf(pv, vk.z, w4.z); w4.w = fmaf(pv, vk.w, w4.w);
    }

    float s1 = (w4.x + w4.y) + (w4.z + w4.w);
    float s2 = (w4.x*w4.x + w4.y*w4.y) + (w4.z*w4.z + w4.w*w4.w);
    s1 += __shfl_xor(s1, 1); s1 += __shfl_xor(s1, 2);
    s2 += __shfl_xor(s2, 1); s2 += __shfl_xor(s2, 2);
    float m   = s1 * (1.f / 16.f);
    float var = s2 * (1.f / 16.f) - m * m;
    float inv = rsqrtf(var + LNEPS);
    float4 gl = *(const float4*)(g_lim + j0);
    float4 bl = *(const float4*)(b_lim + j0);
    float4 o;
    o.x = (w4.x - m) * inv * gl.x + bl.x;
    o.y = (w4.y - m) * inv * gl.y + bl.y;
    o.z = (w4.z - m) * inv * gl.z + bl.z;
    o.w = (w4.w - m) * inv * gl.w + bl.w;
    *(float4*)(combined + ((size_t)tile * CURD + i) * KDIM + j0) = o;

    // fold Wd packing into the first 192 blocks (completes before fused kernel)
    if (blockIdx.x < 192) {
        int idx = blockIdx.x * 256 + threadIdx.x;   // 0 .. 49151 = 96*512
        int k = idx / 512, c = idx % 512;
        float v = (k < KDIM) ? Wd[(size_t)k * OUTD + c] : 0.f;
        unsigned short h = f2bf(v);
        unsigned short l = f2bf(v - bf2f(h));
        int s = k >> 5, kk = k & 31, g = kk >> 3, e = kk & 7;
        size_t o2 = (((size_t)(s * 512 + c)) * 4 + g) * 8 + e;
        whi[o2] = h;
        wlo[o2] = l;
    }
}

// ---------------------------------------------------------------------------
// Kernel 2 (fused): producer rec chains + consumer out GEMM, flag-synced.
// Roles claimed via atomic ticket so rec blocks are guaranteed resident
// (deadlock-free: rec waits on nobody; out waits only on rec progress).
// Bounded spin converts any residual protocol hole into a wrong-answer
// instead of a hung container.
// ---------------------------------------------------------------------------
__global__ __launch_bounds__(256) void fused_kernel(
    const float* __restrict__ Ws, const float* __restrict__ bs,
    const float* __restrict__ g_doubt, const float* __restrict__ b_doubt,
    float* __restrict__ combined,
    const unsigned short* __restrict__ Bhi,
    const unsigned short* __restrict__ Blo,
    const float* __restrict__ bd, const float* __restrict__ g_check,
    const float* __restrict__ b_check, float* __restrict__ out,
    unsigned int* __restrict__ flags)
{
    __shared__ __align__(16) unsigned short Ahi[32][104];
    __shared__ __align__(16) unsigned short Alo[32][104];
    __shared__ float red[4][32][2];
    __shared__ float s_G[4][64];
    __shared__ int s_tk;

    const int tid = threadIdx.x;
    if (tid == 0)
        s_tk = (int)__hip_atomic_fetch_add(&flags[0], 1u,
                    __ATOMIC_RELAXED, __HIP_MEMORY_SCOPE_AGENT);
    __syncthreads();
    const int role_tk = s_tk;

    if (role_tk < NRECB) {
        // ---------------- rec role: 4 chains (one per wave) ----------------
        __builtin_amdgcn_s_setprio(1);
        const int wid = tid >> 6;
        const int c   = tid & 63;
        const int chain = role_tk * 4 + wid;
        const int b = chain >> 4;
        const int r = chain & 15;

        float Wsw[16];
        #pragma unroll
        for (int j = 0; j < 16; ++j) Wsw[j] = Ws[j * HIDD + c];

        float Wsp[64];
        float u = 0.f, w0 = 0.f;
        #pragma unroll
        for (int j = 0; j < 64; ++j) {
            float w   = Ws[(16 + j) * HIDD + c];
            float gdj = g_doubt[j];
            float bdj = b_doubt[j];
            Wsp[j] = gdj * w;
            u += Wsp[j];
            w0 = fmaf(bdj, w, w0);
        }
        const float bsc  = bs[c];
        const float gd_c = g_doubt[c];
        const float bd_c = b_doubt[c];

        size_t rowoff = ((size_t)b * CURD + r) * KDIM;
        const size_t stride = (size_t)BB * CURD * KDIM;

        float4 wc0, wc1, wc2, wc3;
        float4 wn0, wn1, wn2, wn3;
        {
            const float4* p0 = (const float4*)(combined + rowoff);
            wc0 = p0[0]; wc1 = p0[1]; wc2 = p0[2]; wc3 = p0[3];
            const float4* p1 = (const float4*)(combined + rowoff + stride);
            wn0 = p1[0]; wn1 = p1[1]; wn2 = p1[2]; wn3 = p1[3];
        }

        float P = 0.f, mp = 0.f, ip = 0.f, w0f = 0.f;
        float sv_store = 0.f;

        for (int t = 0; t < NCH; ++t) {
            combined[rowoff + 16 + c] = sv_store;

            // slab signal: every 16 chunks, release prior sus stores + count
            if ((t & 15) == 15) {
                __builtin_amdgcn_fence(__ATOMIC_RELEASE, "agent");
                if (c == 0)
                    __hip_atomic_fetch_add(&flags[16 + (t >> 4) * 16], 1u,
                        __ATOMIC_RELAXED, __HIP_MEMORY_SCOPE_AGENT);
            }

            float4 wp0, wp1, wp2, wp3;
            if (t + 2 < NCH) {
                const float4* p2 = (const float4*)(combined + rowoff + 2 * stride);
                wp0 = p2[0]; wp1 = p2[1]; wp2 = p2[2]; wp3 = p2[3];
            } else {
                wp0 = wp1 = wp2 = wp3 = make_float4(0.f, 0.f, 0.f, 0.f);
            }

            float h0 = fmaf(ip, P - mp * u, bsc + w0f);
            float h1 = 0.f, h2 = 0.f, h3 = 0.f;
            h0 = fmaf(wc0.x, Wsw[0],  h0); h1 = fmaf(wc0.y, Wsw[1],  h1);
            h2 = fmaf(wc0.z, Wsw[2],  h2); h3 = fmaf(wc0.w, Wsw[3],  h3);
            h0 = fmaf(wc1.x, Wsw[4],  h0); h1 = fmaf(wc1.y, Wsw[5],  h1);
            h2 = fmaf(wc1.z, Wsw[6],  h2); h3 = fmaf(wc1.w, Wsw[7],  h3);
            h0 = fmaf(wc2.x, Wsw[8],  h0); h1 = fmaf(wc2.y, Wsw[9],  h1);
            h2 = fmaf(wc2.z, Wsw[10], h2); h3 = fmaf(wc2.w, Wsw[11], h3);
            h0 = fmaf(wc3.x, Wsw[12], h0); h1 = fmaf(wc3.y, Wsw[13], h1);
            h2 = fmaf(wc3.z, Wsw[14], h2); h3 = fmaf(wc3.w, Wsw[15], h3);
            float h = (h0 + h1) + (h2 + h3);

            float G = 0.5f * h * (1.f + erff(h * 0.70710678118654752f));

            s_G[wid][c] = G;
            const float4* gp = (const float4*)s_G[wid];
            float4 xr[16];
            #pragma unroll
            for (int j4 = 0; j4 < 16; ++j4) xr[j4] = gp[j4];

            float s1 = wave64_sum(G);
            float s2 = wave64_sum(G * G);
            float m   = s1 * (1.f / 64.f);
            float var = s2 * (1.f / 64.f) - m * m;
            float inv = rsqrtf(var + LNEPS);

            float p0=0.f,p1=0.f,p2=0.f,p3=0.f,p4=0.f,p5=0.f,p6=0.f,p7=0.f;
            #pragma unroll
            for (int j4 = 0; j4 < 16; j4 += 2) {
                float4 x0 = xr[j4], x1 = xr[j4 + 1];
                p0 = fmaf(x0.x, Wsp[4*j4+0], p0);
                p1 = fmaf(x0.y, Wsp[4*j4+1], p1);
                p2 = fmaf(x0.z, Wsp[4*j4+2], p2);
                p3 = fmaf(x0.w, Wsp[4*j4+3], p3);
                p4 = fmaf(x1.x, Wsp[4*j4+4], p4);
                p5 = fmaf(x1.y, Wsp[4*j4+5], p5);
                p6 = fmaf(x1.z, Wsp[4*j4+6], p6);
                p7 = fmaf(x1.w, Wsp[4*j4+7], p7);
            }
            P = ((p0 + p1) + (p2 + p3)) + ((p4 + p5) + (p6 + p7));

            sv_store = fmaf((G - m) * inv, gd_c, bd_c);
            mp = m; ip = inv; w0f = w0;
            wc0 = wn0; wc1 = wn1; wc2 = wn2; wc3 = wn3;
            wn0 = wp0; wn1 = wp1; wn2 = wp2; wn3 = wp3;
            rowoff += stride;
        }
        return;
    }

    // ---------------- out role: task loop over 32-row tiles ----------------
    const int lane  = tid & 63;
    const int wid   = tid >> 6;
    const int arowb = lane & 15;
    const int kg    = lane >> 4;

    int cols[8]; float bdv[8], gcv[8], bcv[8];
    #pragma unroll
    for (int n = 0; n < 8; ++n) {
        cols[n] = wid * 128 + n * 16 + arowb;
        bdv[n] = bd[cols[n]];
        gcv[n] = g_check[cols[n]];
        bcv[n] = b_check[cols[n]];
    }

    for (;;) {
        if (tid == 0)
            s_tk = (int)__hip_atomic_fetch_add(&flags[1], 1u,
                        __ATOMIC_RELAXED, __HIP_MEMORY_SCOPE_AGENT);
        __syncthreads();
        const int task = s_tk;
        if (task >= NTASKS) break;

        const int slab = task >> 8;    // 256 tasks per 16-chunk slab
        if (tid == 0) {
            unsigned guard = 0;
            while (__hip_atomic_load(&flags[16 + slab * 16], __ATOMIC_RELAXED,
                                     __HIP_MEMORY_SCOPE_AGENT) < 512u
                   && guard < (1u << 20)) {
                __builtin_amdgcn_s_sleep(32);
                ++guard;
            }
        }
        __syncthreads();
        __builtin_amdgcn_fence(__ATOMIC_ACQUIRE, "agent");

        const size_t rowbase = (size_t)task * 32;

        // stage + split-convert A (32 rows x 80), zero-pad k in [80,96)
        {
            const float4* src4 = (const float4*)(combined + rowbase * KDIM);
            #pragma unroll
            for (int u2 = 0; u2 < 3; ++u2) {
                int idx = tid + 256 * u2;
                if (idx < 32 * 20) {
                    float4 v = src4[idx];
                    int rr = idx / 20, k4 = idx % 20;
                    float vs[4] = {v.x, v.y, v.z, v.w};
                    #pragma unroll
                    for (int e = 0; e < 4; ++e) {
                        unsigned short h = f2bf(vs[e]);
                        Ahi[rr][k4 * 4 + e] = h;
                        Alo[rr][k4 * 4 + e] = f2bf(vs[e] - bf2f(h));
                    }
                }
            }
            #pragma unroll
            for (int u2 = 0; u2 < 2; ++u2) {
                int idx = tid + 256 * u2;
                int rr = idx >> 4, kk = 80 + (idx & 15);
                Ahi[rr][kk] = 0;
                Alo[rr][kk] = 0;
            }
        }
        __syncthreads();

        bf16x8 a_hi[2][3], a_lo[2][3];
        #pragma unroll
        for (int ms = 0; ms < 2; ++ms)
            #pragma unroll
            for (int s = 0; s < 3; ++s) {
                a_hi[ms][s] = *(const bf16x8*)&Ahi[ms * 16 + arowb][s * 32 + kg * 8];
                a_lo[ms][s] = *(const bf16x8*)&Alo[ms * 16 + arowb][s * 32 + kg * 8];
            }

        f32x4 acc[2][8];
        #pragma unroll
        for (int ms = 0; ms < 2; ++ms)
            #pragma unroll
            for (int n = 0; n < 8; ++n) acc[ms][n] = (f32x4){0.f, 0.f, 0.f, 0.f};

        #pragma unroll
        for (int n = 0; n < 8; ++n) {
            #pragma unroll
            for (int s = 0; s < 3; ++s) {
                size_t off = (((size_t)(s * 512 + cols[n])) * 4 + kg) * 8;
                bf16x8 bh = *(const bf16x8*)(Bhi + off);
                bf16x8 bl = *(const bf16x8*)(Blo + off);
                acc[0][n] = __builtin_amdgcn_mfma_f32_16x16x32_bf16(a_hi[0][s], bh, acc[0][n], 0, 0, 0);
                acc[1][n] = __builtin_amdgcn_mfma_f32_16x16x32_bf16(a_hi[1][s], bh, acc[1][n], 0, 0, 0);
                acc[0][n] = __builtin_amdgcn_mfma_f32_16x16x32_bf16(a_lo[0][s], bh, acc[0][n], 0, 0, 0);
                acc[1][n] = __builtin_amdgcn_mfma_f32_16x16x32_bf16(a_lo[1][s], bh, acc[1][n], 0, 0, 0);
                acc[0][n] = __builtin_amdgcn_mfma_f32_16x16x32_bf16(a_hi[0][s], bl, acc[0][n], 0, 0, 0);
                acc[1][n] = __builtin_amdgcn_mfma_f32_16x16x32_bf16(a_hi[1][s], bl, acc[1][n], 0, 0, 0);
            }
        }

        #pragma unroll
        for (int ms = 0; ms < 2; ++ms) {
            float s1[4] = {0.f, 0.f, 0.f, 0.f};
            float s2[4] = {0.f, 0.f, 0.f, 0.f};
            #pragma unroll
            for (int n = 0; n < 8; ++n) {
                #pragma unroll
                for (int j = 0; j < 4; ++j) {
                    float v = acc[ms][n][j] + bdv[n];
                    acc[ms][n][j] = v;
                    s1[j] += v;
                    s2[j] = fmaf(v, v, s2[j]);
                }
            }
            #pragma unroll
            for (int j = 0; j < 4; ++j) {
                s1[j] = row16_sum(s1[j]);
                s2[j] = row16_sum(s2[j]);
            }
            if (arowb == 0) {
                #pragma unroll
                for (int j = 0; j < 4; ++j) {
                    red[wid][ms * 16 + kg * 4 + j][0] = s1[j];
                    red[wid][ms * 16 + kg * 4 + j][1] = s2[j];
                }
            }
        }
        __syncthreads();

        #pragma unroll
        for (int ms = 0; ms < 2; ++ms) {
            #pragma unroll
            for (int j = 0; j < 4; ++j) {
                const int rowl = ms * 16 + kg * 4 + j;
                float t1 = (red[0][rowl][0] + red[1][rowl][0])
                         + (red[2][rowl][0] + red[3][rowl][0]);
                float t2 = (red[0][rowl][1] + red[1][rowl][1])
                         + (red[2][rowl][1] + red[3][rowl][1]);
                float mm  = t1 * (1.f / 512.f);
                float var = t2 * (1.f / 512.f) - mm * mm;
                float iv  = rsqrtf(var + LNEPS);

                size_t R = rowbase + (size_t)rowl;
                int ii  = (int)(R & 15);
                int bb2 = (int)((R >> 4) & 31);
                int tt  = (int)(R >> 9);
                size_t orow = ((size_t)bb2 * SS + (size_t)tt * CURD + ii) * OUTD;

                #pragma unroll
                for (int n = 0; n < 8; ++n) {
                    out[orow + cols[n]] =
                        (acc[ms][n][j] - mm) * iv * gcv[n] + bcv[n];
                }
            }
        }
        __syncthreads();
    }
}

// ---------------------------------------------------------------------------
extern "C" void kernel_launch(void* const* d_in, const int* in_sizes, int n_in,
                              void* d_out, int out_size, void* d_ws, size_t ws_size,
                              hipStream_t stream)
{
    const int*   x       = (const int*)  d_in[0];
    const float* emb     = (const float*)d_in[1];
    const float* Wq      = (const float*)d_in[2];
    const float* bq      = (const float*)d_in[3];
    const float* Wk      = (const float*)d_in[4];
    const float* bk      = (const float*)d_in[5];
    const float* Wv      = (const float*)d_in[6];
    const float* bv      = (const float*)d_in[7];
    const float* g_lim   = (const float*)d_in[8];
    const float* b_lim   = (const float*)d_in[9];
    const float* Ws      = (const float*)d_in[10];
    const float* bs      = (const float*)d_in[11];
    const float* g_doubt = (const float*)d_in[12];
    const float* b_doubt = (const float*)d_in[13];
    const float* Wd      = (const float*)d_in[14];
    const float* bd      = (const float*)d_in[15];
    const float* g_check = (const float*)d_in[16];
    const float* b_check = (const float*)d_in[17];

    float* out      = (float*)d_out;
    float* combined = (float*)d_ws;    // [NCH][BB][CURD][KDIM] fp32 = 40 MB
    unsigned short* whi = (unsigned short*)((char*)d_ws + WS_WHI);
    unsigned short* wlo = (unsigned short*)((char*)d_ws + WS_WLO);
    unsigned int*  flags = (unsigned int*)((char*)d_ws + WS_FLAGS);

    attn_kernel<<<dim3(NCH * BB / 4), dim3(256), 0, stream>>>(
        x, emb, Wq, bq, Wk, bk, Wv, bv, g_lim, b_lim, combined,
        Wd, whi, wlo, flags);

    fused_kernel<<<dim3(NRECB + NOUTB), dim3(256), 0, stream>>>(
        Ws, bs, g_doubt, b_doubt, combined, whi, wlo,
        bd, g_check, b_check, out, flags);
}

// Round 4
// 579.276 us; speedup vs baseline: 1.3434x; 1.3434x over previous
//
#include <hip/hip_runtime.h>
#include <math.h>

#define VOCN 50257
#define OUTD 512
#define HIDD 64
#define CURD 16
#define BB   32
#define SS   4096
#define NCH  256      // SS / CURD
#define KDIM 80       // HIDD + CURD
#define LNEPS 1e-5f

// workspace layout
#define WS_WHI   41943040                  // combined = [0, 40MB)
#define WS_WLO   (WS_WHI + 96*512*2)
#define WS_FLAGS (WS_WLO + 96*512*2)       // 512 u32: [0]=role tkt [1]=task tkt
#define NRECB    128                       // rec blocks (4 chains each)
#define NOUTB    512
#define NTASKS   4096                      // 131072 rows / 32
#define NSLABS   16                        // 16 chunks per slab
// ready[slab] lives at flags[16 + slab*16]  (64B apart, own cacheline)

// ---------------------------------------------------------------------------
// helpers
// ---------------------------------------------------------------------------
#define DPP_ADD(x, ctrl) \
    ((x) + __int_as_float(__builtin_amdgcn_update_dpp( \
        0, __float_as_int(x), (ctrl), 0xf, 0xf, true)))

__device__ __forceinline__ float row16_sum(float x) {
    x = DPP_ADD(x, 0xB1);   // quad_perm xor1
    x = DPP_ADD(x, 0x4E);   // quad_perm xor2
    x = DPP_ADD(x, 0x141);  // row_half_mirror xor4
    x = DPP_ADD(x, 0x140);  // row_mirror xor8
    return x;
}

__device__ __forceinline__ float wave64_sum(float x) {
    float r = row16_sum(x);
    float a = __int_as_float(__builtin_amdgcn_readlane(__float_as_int(r), 0));
    float b = __int_as_float(__builtin_amdgcn_readlane(__float_as_int(r), 16));
    float c = __int_as_float(__builtin_amdgcn_readlane(__float_as_int(r), 32));
    float d = __int_as_float(__builtin_amdgcn_readlane(__float_as_int(r), 48));
    return (a + b) + (c + d);
}

__device__ __forceinline__ unsigned short f2bf(float x) {
    unsigned u = __float_as_uint(x);
    u += 0x7fffu + ((u >> 16) & 1u);
    return (unsigned short)(u >> 16);
}
__device__ __forceinline__ float bf2f(unsigned short h) {
    return __uint_as_float(((unsigned)h) << 16);
}

typedef __attribute__((ext_vector_type(8))) short bf16x8;
typedef __attribute__((ext_vector_type(4))) float f32x4;

// ---------------------------------------------------------------------------
// Kernel 1: attention (unchanged math) + flag zeroing + Wd packing folded in.
// ---------------------------------------------------------------------------
__global__ __launch_bounds__(256) void attn_kernel(
    const int* __restrict__ x, const float* __restrict__ emb,
    const float* __restrict__ Wq, const float* __restrict__ bq,
    const float* __restrict__ Wk, const float* __restrict__ bk,
    const float* __restrict__ Wv, const float* __restrict__ bv,
    const float* __restrict__ g_lim, const float* __restrict__ b_lim,
    float* __restrict__ combined,
    const float* __restrict__ Wd,
    unsigned short* __restrict__ whi, unsigned short* __restrict__ wlo,
    unsigned int* __restrict__ flags)
{
    if (blockIdx.x == 0) {
        flags[threadIdx.x] = 0u;
        flags[threadIdx.x + 256] = 0u;
    }

    const int wid  = threadIdx.x >> 6;
    const int lane = threadIdx.x & 63;
    const int tile = blockIdx.x * 4 + wid;
    const int t = tile >> 5, b = tile & 31;
    const int i  = lane >> 2;
    const int jg = lane & 3;
    const int j0 = jg * 4;

    __shared__ __align__(16) float ldsT[4][4][16][20];
    float (*R)[20] = ldsT[wid][0];
    float (*Q)[20] = ldsT[wid][1];
    float (*K)[20] = ldsT[wid][2];
    float (*V)[20] = ldsT[wid][3];

    int myid = 0;
    if (lane < 16) myid = x[b * SS + t * CURD + lane];
    const int id_i = __shfl(myid, i, 64);

    float4 r4 = *(const float4*)(emb + (size_t)id_i * CURD + j0);
    *(float4*)&R[i][j0] = r4;

    float rrow[16];
    {
        float4 t0 = *(const float4*)&R[i][0];
        float4 t1 = *(const float4*)&R[i][4];
        float4 t2 = *(const float4*)&R[i][8];
        float4 t3 = *(const float4*)&R[i][12];
        rrow[0]=t0.x; rrow[1]=t0.y; rrow[2]=t0.z;  rrow[3]=t0.w;
        rrow[4]=t1.x; rrow[5]=t1.y; rrow[6]=t1.z;  rrow[7]=t1.w;
        rrow[8]=t2.x; rrow[9]=t2.y; rrow[10]=t2.z; rrow[11]=t2.w;
        rrow[12]=t3.x; rrow[13]=t3.y; rrow[14]=t3.z; rrow[15]=t3.w;
    }

    float4 q4 = *(const float4*)(bq + j0);
    float4 k4 = *(const float4*)(bk + j0);
    float4 v4 = *(const float4*)(bv + j0);
    #pragma unroll
    for (int k = 0; k < 16; ++k) {
        float rv = rrow[k];
        float4 wq4 = *(const float4*)(Wq + k * CURD + j0);
        float4 wk4 = *(const float4*)(Wk + k * CURD + j0);
        float4 wv4 = *(const float4*)(Wv + k * CURD + j0);
        q4.x = fmaf(rv, wq4.x, q4.x); q4.y = fmaf(rv, wq4.y, q4.y);
        q4.z = fmaf(rv, wq4.z, q4.z); q4.w = fmaf(rv, wq4.w, q4.w);
        k4.x = fmaf(rv, wk4.x, k4.x); k4.y = fmaf(rv, wk4.y, k4.y);
        k4.z = fmaf(rv, wk4.z, k4.z); k4.w = fmaf(rv, wk4.w, k4.w);
        v4.x = fmaf(rv, wv4.x, v4.x); v4.y = fmaf(rv, wv4.y, v4.y);
        v4.z = fmaf(rv, wv4.z, v4.z); v4.w = fmaf(rv, wv4.w, v4.w);
    }
    *(float4*)&Q[i][j0] = q4;
    *(float4*)&K[i][j0] = k4;
    *(float4*)&V[i][j0] = v4;

    float qrow[16];
    {
        float4 t0 = *(const float4*)&Q[i][0];
        float4 t1 = *(const float4*)&Q[i][4];
        float4 t2 = *(const float4*)&Q[i][8];
        float4 t3 = *(const float4*)&Q[i][12];
        qrow[0]=t0.x; qrow[1]=t0.y; qrow[2]=t0.z;  qrow[3]=t0.w;
        qrow[4]=t1.x; qrow[5]=t1.y; qrow[6]=t1.z;  qrow[7]=t1.w;
        qrow[8]=t2.x; qrow[9]=t2.y; qrow[10]=t2.z; qrow[11]=t2.w;
        qrow[12]=t3.x; qrow[13]=t3.y; qrow[14]=t3.z; qrow[15]=t3.w;
    }
    float sc[4];
    #pragma unroll
    for (int jj = 0; jj < 4; ++jj) {
        const int row = j0 + jj;
        float4 c0 = *(const float4*)&K[row][0];
        float4 c1 = *(const float4*)&K[row][4];
        float4 c2 = *(const float4*)&K[row][8];
        float4 c3 = *(const float4*)&K[row][12];
        float d0 = qrow[0]*c0.x + qrow[1]*c0.y + qrow[2]*c0.z + qrow[3]*c0.w;
        float d1 = qrow[4]*c1.x + qrow[5]*c1.y + qrow[6]*c1.z + qrow[7]*c1.w;
        float d2 = qrow[8]*c2.x + qrow[9]*c2.y + qrow[10]*c2.z + qrow[11]*c2.w;
        float d3 = qrow[12]*c3.x + qrow[13]*c3.y + qrow[14]*c3.z + qrow[15]*c3.w;
        sc[jj] = ((d0 + d1) + (d2 + d3)) * 0.25f;
    }

    float mx = fmaxf(fmaxf(sc[0], sc[1]), fmaxf(sc[2], sc[3]));
    mx = fmaxf(mx, __shfl_xor(mx, 1));
    mx = fmaxf(mx, __shfl_xor(mx, 2));
    float e0 = expf(sc[0]-mx), e1 = expf(sc[1]-mx),
          e2 = expf(sc[2]-mx), e3 = expf(sc[3]-mx);
    float es = (e0 + e1) + (e2 + e3);
    es += __shfl_xor(es, 1);
    es += __shfl_xor(es, 2);
    float rs = 1.f / es;
    float4 p4 = make_float4(e0*rs, e1*rs, e2*rs, e3*rs);
    *(float4*)&R[i][j0] = p4;

    float prow[16];
    {
        float4 t0 = *(const float4*)&R[i][0];
        float4 t1 = *(const float4*)&R[i][4];
        float4 t2 = *(const float4*)&R[i][8];
        float4 t3 = *(const float4*)&R[i][12];
        prow[0]=t0.x; prow[1]=t0.y; prow[2]=t0.z;  prow[3]=t0.w;
        prow[4]=t1.x; prow[5]=t1.y; prow[6]=t1.z;  prow[7]=t1.w;
        prow[8]=t2.x; prow[9]=t2.y; prow[10]=t2.z; prow[11]=t2.w;
        prow[12]=t3.x; prow[13]=t3.y; prow[14]=t3.z; prow[15]=t3.w;
    }
    float4 w4 = make_float4(0.f, 0.f, 0.f, 0.f);
    #pragma unroll
    for (int k = 0; k < 16; ++k) {
        float4 vk = *(const float4*)&V[k][j0];
        float pv = prow[k];
        w4.x = fmaf(pv, vk.x, w4.x); w4.y = fmaf(pv, vk.y, w4.y);
        w4.z = fmaf(pv, vk.z, w4.z); w4.w = fmaf(pv, vk.w, w4.w);
    }

    float s1 = (w4.x + w4.y) + (w4.z + w4.w);
    float s2 = (w4.x*w4.x + w4.y*w4.y) + (w4.z*w4.z + w4.w*w4.w);
    s1 += __shfl_xor(s1, 1); s1 += __shfl_xor(s1, 2);
    s2 += __shfl_xor(s2, 1); s2 += __shfl_xor(s2, 2);
    float m   = s1 * (1.f / 16.f);
    float var = s2 * (1.f / 16.f) - m * m;
    float inv = rsqrtf(var + LNEPS);
    float4 gl = *(const float4*)(g_lim + j0);
    float4 bl = *(const float4*)(b_lim + j0);
    float4 o;
    o.x = (w4.x - m) * inv * gl.x + bl.x;
    o.y = (w4.y - m) * inv * gl.y + bl.y;
    o.z = (w4.z - m) * inv * gl.z + bl.z;
    o.w = (w4.w - m) * inv * gl.w + bl.w;
    *(float4*)(combined + ((size_t)tile * CURD + i) * KDIM + j0) = o;

    // fold Wd packing into the first 192 blocks (completes before fused kernel)
    if (blockIdx.x < 192) {
        int idx = blockIdx.x * 256 + threadIdx.x;   // 0 .. 49151 = 96*512
        int k = idx / 512, c = idx % 512;
        float v = (k < KDIM) ? Wd[(size_t)k * OUTD + c] : 0.f;
        unsigned short h = f2bf(v);
        unsigned short l = f2bf(v - bf2f(h));
        int s = k >> 5, kk = k & 31, g = kk >> 3, e = kk & 7;
        size_t o2 = (((size_t)(s * 512 + c)) * 4 + g) * 8 + e;
        whi[o2] = h;
        wlo[o2] = l;
    }
}

// ---------------------------------------------------------------------------
// Kernel 2 (fused): producer rec chains + consumer out GEMM, flag-synced.
// __launch_bounds__(256, 1): rec's ~200-reg working set MUST stay in VGPRs —
// round-3's 144-reg allocation spilled the serial chain to scratch (8x slow).
// Sync protocol (no agent fences): sus stores are agent-scope write-through
// atomics; producer orders them with s_waitcnt vmcnt(0) before the slab
// atomicAdd. Consumers first-touch the sus cache lines (distinct 64B lines
// from the watch lines: rows are 320B) only after the flag, so no stale L1/L2
// copies can exist; cross-iteration staleness is killed by kernel-boundary
// cache invalidation (same guarantee the 3-kernel pipeline relied on).
// ---------------------------------------------------------------------------
__global__ __launch_bounds__(256, 1) void fused_kernel(
    const float* __restrict__ Ws, const float* __restrict__ bs,
    const float* __restrict__ g_doubt, const float* __restrict__ b_doubt,
    float* __restrict__ combined,
    const unsigned short* __restrict__ Bhi,
    const unsigned short* __restrict__ Blo,
    const float* __restrict__ bd, const float* __restrict__ g_check,
    const float* __restrict__ b_check, float* __restrict__ out,
    unsigned int* __restrict__ flags)
{
    __shared__ __align__(16) unsigned short Ahi[32][104];
    __shared__ __align__(16) unsigned short Alo[32][104];
    __shared__ float red[4][32][2];
    __shared__ float s_G[4][64];
    __shared__ int s_tk;

    const int tid = threadIdx.x;
    if (tid == 0)
        s_tk = (int)__hip_atomic_fetch_add(&flags[0], 1u,
                    __ATOMIC_RELAXED, __HIP_MEMORY_SCOPE_AGENT);
    __syncthreads();
    const int role_tk = s_tk;

    if (role_tk < NRECB) {
        // ---------------- rec role: 4 chains (one per wave) ----------------
        __builtin_amdgcn_s_setprio(1);
        const int wid = tid >> 6;
        const int c   = tid & 63;
        const int chain = role_tk * 4 + wid;
        const int b = chain >> 4;
        const int r = chain & 15;

        float Wsw[16];
        #pragma unroll
        for (int j = 0; j < 16; ++j) Wsw[j] = Ws[j * HIDD + c];

        float Wsp[64];
        float u = 0.f, w0 = 0.f;
        #pragma unroll
        for (int j = 0; j < 64; ++j) {
            float w   = Ws[(16 + j) * HIDD + c];
            float gdj = g_doubt[j];
            float bdj = b_doubt[j];
            Wsp[j] = gdj * w;
            u += Wsp[j];
            w0 = fmaf(bdj, w, w0);
        }
        const float bsc  = bs[c];
        const float gd_c = g_doubt[c];
        const float bd_c = b_doubt[c];

        size_t rowoff = ((size_t)b * CURD + r) * KDIM;
        const size_t stride = (size_t)BB * CURD * KDIM;

        float4 wc0, wc1, wc2, wc3;
        float4 wn0, wn1, wn2, wn3;
        {
            const float4* p0 = (const float4*)(combined + rowoff);
            wc0 = p0[0]; wc1 = p0[1]; wc2 = p0[2]; wc3 = p0[3];
            const float4* p1 = (const float4*)(combined + rowoff + stride);
            wn0 = p1[0]; wn1 = p1[1]; wn2 = p1[2]; wn3 = p1[3];
        }

        float P = 0.f, mp = 0.f, ip = 0.f, w0f = 0.f;
        float sv_store = 0.f;

        for (int t = 0; t < NCH; ++t) {
            // fire-and-forget write-through store (visible at coherent point)
            __hip_atomic_store(&combined[rowoff + 16 + c], sv_store,
                               __ATOMIC_RELAXED, __HIP_MEMORY_SCOPE_AGENT);

            // slab signal: every 16 chunks. vmcnt(0) orders the sus stores
            // (already write-through) before the flag RMW — no L2 writeback.
            if ((t & 15) == 15) {
                asm volatile("s_waitcnt vmcnt(0)" ::: "memory");
                if (c == 0)
                    __hip_atomic_fetch_add(&flags[16 + (t >> 4) * 16], 1u,
                        __ATOMIC_RELAXED, __HIP_MEMORY_SCOPE_AGENT);
            }

            float4 wp0, wp1, wp2, wp3;
            if (t + 2 < NCH) {
                const float4* p2 = (const float4*)(combined + rowoff + 2 * stride);
                wp0 = p2[0]; wp1 = p2[1]; wp2 = p2[2]; wp3 = p2[3];
            } else {
                wp0 = wp1 = wp2 = wp3 = make_float4(0.f, 0.f, 0.f, 0.f);
            }

            float h0 = fmaf(ip, P - mp * u, bsc + w0f);
            float h1 = 0.f, h2 = 0.f, h3 = 0.f;
            h0 = fmaf(wc0.x, Wsw[0],  h0); h1 = fmaf(wc0.y, Wsw[1],  h1);
            h2 = fmaf(wc0.z, Wsw[2],  h2); h3 = fmaf(wc0.w, Wsw[3],  h3);
            h0 = fmaf(wc1.x, Wsw[4],  h0); h1 = fmaf(wc1.y, Wsw[5],  h1);
            h2 = fmaf(wc1.z, Wsw[6],  h2); h3 = fmaf(wc1.w, Wsw[7],  h3);
            h0 = fmaf(wc2.x, Wsw[8],  h0); h1 = fmaf(wc2.y, Wsw[9],  h1);
            h2 = fmaf(wc2.z, Wsw[10], h2); h3 = fmaf(wc2.w, Wsw[11], h3);
            h0 = fmaf(wc3.x, Wsw[12], h0); h1 = fmaf(wc3.y, Wsw[13], h1);
            h2 = fmaf(wc3.z, Wsw[14], h2); h3 = fmaf(wc3.w, Wsw[15], h3);
            float h = (h0 + h1) + (h2 + h3);

            float G = 0.5f * h * (1.f + erff(h * 0.70710678118654752f));

            s_G[wid][c] = G;
            const float4* gp = (const float4*)s_G[wid];

            float s1 = wave64_sum(G);
            float s2 = wave64_sum(G * G);
            float m   = s1 * (1.f / 64.f);
            float var = s2 * (1.f / 64.f) - m * m;
            float inv = rsqrtf(var + LNEPS);

            // P = sum_j G_j * Wsp_j — batched 4x4 float4 to cap live regs
            float p0=0.f,p1=0.f,p2=0.f,p3=0.f,p4=0.f,p5=0.f,p6=0.f,p7=0.f;
            #pragma unroll
            for (int bq = 0; bq < 4; ++bq) {
                float4 x0 = gp[bq*4+0], x1 = gp[bq*4+1];
                float4 x2 = gp[bq*4+2], x3 = gp[bq*4+3];
                p0 = fmaf(x0.x, Wsp[16*bq+0],  p0);
                p1 = fmaf(x0.y, Wsp[16*bq+1],  p1);
                p2 = fmaf(x0.z, Wsp[16*bq+2],  p2);
                p3 = fmaf(x0.w, Wsp[16*bq+3],  p3);
                p4 = fmaf(x1.x, Wsp[16*bq+4],  p4);
                p5 = fmaf(x1.y, Wsp[16*bq+5],  p5);
                p6 = fmaf(x1.z, Wsp[16*bq+6],  p6);
                p7 = fmaf(x1.w, Wsp[16*bq+7],  p7);
                p0 = fmaf(x2.x, Wsp[16*bq+8],  p0);
                p1 = fmaf(x2.y, Wsp[16*bq+9],  p1);
                p2 = fmaf(x2.z, Wsp[16*bq+10], p2);
                p3 = fmaf(x2.w, Wsp[16*bq+11], p3);
                p4 = fmaf(x3.x, Wsp[16*bq+12], p4);
                p5 = fmaf(x3.y, Wsp[16*bq+13], p5);
                p6 = fmaf(x3.z, Wsp[16*bq+14], p6);
                p7 = fmaf(x3.w, Wsp[16*bq+15], p7);
            }
            P = ((p0 + p1) + (p2 + p3)) + ((p4 + p5) + (p6 + p7));

            sv_store = fmaf((G - m) * inv, gd_c, bd_c);
            mp = m; ip = inv; w0f = w0;
            wc0 = wn0; wc1 = wn1; wc2 = wn2; wc3 = wn3;
            wn0 = wp0; wn1 = wp1; wn2 = wp2; wn3 = wp3;
            rowoff += stride;
        }
        return;
    }

    // ---------------- out role: task loop over 32-row tiles ----------------
    const int lane  = tid & 63;
    const int wid   = tid >> 6;
    const int arowb = lane & 15;
    const int kg    = lane >> 4;

    int cols[8]; float bdv[8], gcv[8], bcv[8];
    #pragma unroll
    for (int n = 0; n < 8; ++n) {
        cols[n] = wid * 128 + n * 16 + arowb;
        bdv[n] = bd[cols[n]];
        gcv[n] = g_check[cols[n]];
        bcv[n] = b_check[cols[n]];
    }

    for (;;) {
        if (tid == 0)
            s_tk = (int)__hip_atomic_fetch_add(&flags[1], 1u,
                        __ATOMIC_RELAXED, __HIP_MEMORY_SCOPE_AGENT);
        __syncthreads();
        const int task = s_tk;
        if (task >= NTASKS) break;

        const int slab = task >> 8;    // 256 tasks per 16-chunk slab
        if (tid == 0) {
            unsigned guard = 0;
            while (__hip_atomic_load(&flags[16 + slab * 16], __ATOMIC_RELAXED,
                                     __HIP_MEMORY_SCOPE_AGENT) < 512u
                   && guard < (1u << 20)) {
                __builtin_amdgcn_s_sleep(32);
                ++guard;
            }
        }
        __syncthreads();
        asm volatile("" ::: "memory");   // compiler barrier (no cache ops)

        const size_t rowbase = (size_t)task * 32;

        // stage + split-convert A (32 rows x 80), zero-pad k in [80,96)
        {
            const float4* src4 = (const float4*)(combined + rowbase * KDIM);
            #pragma unroll
            for (int u2 = 0; u2 < 3; ++u2) {
                int idx = tid + 256 * u2;
                if (idx < 32 * 20) {
                    float4 v = src4[idx];
                    int rr = idx / 20, k4 = idx % 20;
                    float vs[4] = {v.x, v.y, v.z, v.w};
                    #pragma unroll
                    for (int e = 0; e < 4; ++e) {
                        unsigned short h = f2bf(vs[e]);
                        Ahi[rr][k4 * 4 + e] = h;
                        Alo[rr][k4 * 4 + e] = f2bf(vs[e] - bf2f(h));
                    }
                }
            }
            #pragma unroll
            for (int u2 = 0; u2 < 2; ++u2) {
                int idx = tid + 256 * u2;
                int rr = idx >> 4, kk = 80 + (idx & 15);
                Ahi[rr][kk] = 0;
                Alo[rr][kk] = 0;
            }
        }
        __syncthreads();

        bf16x8 a_hi[2][3], a_lo[2][3];
        #pragma unroll
        for (int ms = 0; ms < 2; ++ms)
            #pragma unroll
            for (int s = 0; s < 3; ++s) {
                a_hi[ms][s] = *(const bf16x8*)&Ahi[ms * 16 + arowb][s * 32 + kg * 8];
                a_lo[ms][s] = *(const bf16x8*)&Alo[ms * 16 + arowb][s * 32 + kg * 8];
            }

        f32x4 acc[2][8];
        #pragma unroll
        for (int ms = 0; ms < 2; ++ms)
            #pragma unroll
            for (int n = 0; n < 8; ++n) acc[ms][n] = (f32x4){0.f, 0.f, 0.f, 0.f};

        #pragma unroll
        for (int n = 0; n < 8; ++n) {
            #pragma unroll
            for (int s = 0; s < 3; ++s) {
                size_t off = (((size_t)(s * 512 + cols[n])) * 4 + kg) * 8;
                bf16x8 bh = *(const bf16x8*)(Bhi + off);
                bf16x8 bl = *(const bf16x8*)(Blo + off);
                acc[0][n] = __builtin_amdgcn_mfma_f32_16x16x32_bf16(a_hi[0][s], bh, acc[0][n], 0, 0, 0);
                acc[1][n] = __builtin_amdgcn_mfma_f32_16x16x32_bf16(a_hi[1][s], bh, acc[1][n], 0, 0, 0);
                acc[0][n] = __builtin_amdgcn_mfma_f32_16x16x32_bf16(a_lo[0][s], bh, acc[0][n], 0, 0, 0);
                acc[1][n] = __builtin_amdgcn_mfma_f32_16x16x32_bf16(a_lo[1][s], bh, acc[1][n], 0, 0, 0);
                acc[0][n] = __builtin_amdgcn_mfma_f32_16x16x32_bf16(a_hi[0][s], bl, acc[0][n], 0, 0, 0);
                acc[1][n] = __builtin_amdgcn_mfma_f32_16x16x32_bf16(a_hi[1][s], bl, acc[1][n], 0, 0, 0);
            }
        }

        #pragma unroll
        for (int ms = 0; ms < 2; ++ms) {
            float s1[4] = {0.f, 0.f, 0.f, 0.f};
            float s2[4] = {0.f, 0.f, 0.f, 0.f};
            #pragma unroll
            for (int n = 0; n < 8; ++n) {
                #pragma unroll
                for (int j = 0; j < 4; ++j) {
                    float v = acc[ms][n][j] + bdv[n];
                    acc[ms][n][j] = v;
                    s1[j] += v;
                    s2[j] = fmaf(v, v, s2[j]);
                }
            }
            #pragma unroll
            for (int j = 0; j < 4; ++j) {
                s1[j] = row16_sum(s1[j]);
                s2[j] = row16_sum(s2[j]);
            }
            if (arowb == 0) {
                #pragma unroll
                for (int j = 0; j < 4; ++j) {
                    red[wid][ms * 16 + kg * 4 + j][0] = s1[j];
                    red[wid][ms * 16 + kg * 4 + j][1] = s2[j];
                }
            }
        }
        __syncthreads();

        #pragma unroll
        for (int ms = 0; ms < 2; ++ms) {
            #pragma unroll
            for (int j = 0; j < 4; ++j) {
                const int rowl = ms * 16 + kg * 4 + j;
                float t1 = (red[0][rowl][0] + red[1][rowl][0])
                         + (red[2][rowl][0] + red[3][rowl][0]);
                float t2 = (red[0][rowl][1] + red[1][rowl][1])
                         + (red[2][rowl][1] + red[3][rowl][1]);
                float mm  = t1 * (1.f / 512.f);
                float var = t2 * (1.f / 512.f) - mm * mm;
                float iv  = rsqrtf(var + LNEPS);

                size_t R = rowbase + (size_t)rowl;
                int ii  = (int)(R & 15);
                int bb2 = (int)((R >> 4) & 31);
                int tt  = (int)(R >> 9);
                size_t orow = ((size_t)bb2 * SS + (size_t)tt * CURD + ii) * OUTD;

                #pragma unroll
                for (int n = 0; n < 8; ++n) {
                    out[orow + cols[n]] =
                        (acc[ms][n][j] - mm) * iv * gcv[n] + bcv[n];
                }
            }
        }
        __syncthreads();
    }
}

// ---------------------------------------------------------------------------
extern "C" void kernel_launch(void* const* d_in, const int* in_sizes, int n_in,
                              void* d_out, int out_size, void* d_ws, size_t ws_size,
                              hipStream_t stream)
{
    const int*   x       = (const int*)  d_in[0];
    const float* emb     = (const float*)d_in[1];
    const float* Wq      = (const float*)d_in[2];
    const float* bq      = (const float*)d_in[3];
    const float* Wk      = (const float*)d_in[4];
    const float* bk      = (const float*)d_in[5];
    const float* Wv      = (const float*)d_in[6];
    const float* bv      = (const float*)d_in[7];
    const float* g_lim   = (const float*)d_in[8];
    const float* b_lim   = (const float*)d_in[9];
    const float* Ws      = (const float*)d_in[10];
    const float* bs      = (const float*)d_in[11];
    const float* g_doubt = (const float*)d_in[12];
    const float* b_doubt = (const float*)d_in[13];
    const float* Wd      = (const float*)d_in[14];
    const float* bd      = (const float*)d_in[15];
    const float* g_check = (const float*)d_in[16];
    const float* b_check = (const float*)d_in[17];

    float* out      = (float*)d_out;
    float* combined = (float*)d_ws;    // [NCH][BB][CURD][KDIM] fp32 = 40 MB
    unsigned short* whi = (unsigned short*)((char*)d_ws + WS_WHI);
    unsigned short* wlo = (unsigned short*)((char*)d_ws + WS_WLO);
    unsigned int*  flags = (unsigned int*)((char*)d_ws + WS_FLAGS);

    attn_kernel<<<dim3(NCH * BB / 4), dim3(256), 0, stream>>>(
        x, emb, Wq, bq, Wk, bk, Wv, bv, g_lim, b_lim, combined,
        Wd, whi, wlo, flags);

    fused_kernel<<<dim3(NRECB + NOUTB), dim3(256), 0, stream>>>(
        Ws, bs, g_doubt, b_doubt, combined, whi, wlo,
        bd, g_check, b_check, out, flags);
}

// Round 5
// 552.834 us; speedup vs baseline: 1.4077x; 1.0478x over previous
//
#include <hip/hip_runtime.h>
#include <math.h>

#define VOCN 50257
#define OUTD 512
#define HIDD 64
#define CURD 16
#define BB   32
#define SS   4096
#define NCH  256      // SS / CURD
#define KDIM 80       // HIDD + CURD
#define LNEPS 1e-5f

// workspace layout
#define WS_WHI   41943040                  // combined = [0, 40MB)
#define WS_WLO   (WS_WHI + 96*512*2)
#define WS_FLAGS (WS_WLO + 96*512*2)       // 512 u32: [0]=role tkt [1]=task tkt
#define NRECB    256                       // rec blocks (2 chains each, waves 0-1)
#define NOUTB    512
#define NTASKS   4096                      // 131072 rows / 32
#define NSLABS   16                        // 16 chunks per slab
// ready[slab] lives at flags[16 + slab*16]  (64B apart, own cacheline)

// ---------------------------------------------------------------------------
// helpers
// ---------------------------------------------------------------------------
#define DPP_ADD(x, ctrl) \
    ((x) + __int_as_float(__builtin_amdgcn_update_dpp( \
        0, __float_as_int(x), (ctrl), 0xf, 0xf, true)))

__device__ __forceinline__ float row16_sum(float x) {
    x = DPP_ADD(x, 0xB1);   // quad_perm xor1
    x = DPP_ADD(x, 0x4E);   // quad_perm xor2
    x = DPP_ADD(x, 0x141);  // row_half_mirror xor4
    x = DPP_ADD(x, 0x140);  // row_mirror xor8
    return x;
}

__device__ __forceinline__ float wave64_sum(float x) {
    float r = row16_sum(x);
    float a = __int_as_float(__builtin_amdgcn_readlane(__float_as_int(r), 0));
    float b = __int_as_float(__builtin_amdgcn_readlane(__float_as_int(r), 16));
    float c = __int_as_float(__builtin_amdgcn_readlane(__float_as_int(r), 32));
    float d = __int_as_float(__builtin_amdgcn_readlane(__float_as_int(r), 48));
    return (a + b) + (c + d);
}

__device__ __forceinline__ unsigned short f2bf(float x) {
    unsigned u = __float_as_uint(x);
    u += 0x7fffu + ((u >> 16) & 1u);
    return (unsigned short)(u >> 16);
}
__device__ __forceinline__ float bf2f(unsigned short h) {
    return __uint_as_float(((unsigned)h) << 16);
}

typedef __attribute__((ext_vector_type(8))) short bf16x8;
typedef __attribute__((ext_vector_type(4))) float f32x4;

// ---------------------------------------------------------------------------
// Kernel 1: attention (unchanged math) + flag zeroing + Wd packing folded in.
// ---------------------------------------------------------------------------
__global__ __launch_bounds__(256) void attn_kernel(
    const int* __restrict__ x, const float* __restrict__ emb,
    const float* __restrict__ Wq, const float* __restrict__ bq,
    const float* __restrict__ Wk, const float* __restrict__ bk,
    const float* __restrict__ Wv, const float* __restrict__ bv,
    const float* __restrict__ g_lim, const float* __restrict__ b_lim,
    float* __restrict__ combined,
    const float* __restrict__ Wd,
    unsigned short* __restrict__ whi, unsigned short* __restrict__ wlo,
    unsigned int* __restrict__ flags)
{
    if (blockIdx.x == 0) {
        flags[threadIdx.x] = 0u;
        flags[threadIdx.x + 256] = 0u;
    }

    const int wid  = threadIdx.x >> 6;
    const int lane = threadIdx.x & 63;
    const int tile = blockIdx.x * 4 + wid;
    const int t = tile >> 5, b = tile & 31;
    const int i  = lane >> 2;
    const int jg = lane & 3;
    const int j0 = jg * 4;

    __shared__ __align__(16) float ldsT[4][4][16][20];
    float (*R)[20] = ldsT[wid][0];
    float (*Q)[20] = ldsT[wid][1];
    float (*K)[20] = ldsT[wid][2];
    float (*V)[20] = ldsT[wid][3];

    int myid = 0;
    if (lane < 16) myid = x[b * SS + t * CURD + lane];
    const int id_i = __shfl(myid, i, 64);

    float4 r4 = *(const float4*)(emb + (size_t)id_i * CURD + j0);
    *(float4*)&R[i][j0] = r4;

    float rrow[16];
    {
        float4 t0 = *(const float4*)&R[i][0];
        float4 t1 = *(const float4*)&R[i][4];
        float4 t2 = *(const float4*)&R[i][8];
        float4 t3 = *(const float4*)&R[i][12];
        rrow[0]=t0.x; rrow[1]=t0.y; rrow[2]=t0.z;  rrow[3]=t0.w;
        rrow[4]=t1.x; rrow[5]=t1.y; rrow[6]=t1.z;  rrow[7]=t1.w;
        rrow[8]=t2.x; rrow[9]=t2.y; rrow[10]=t2.z; rrow[11]=t2.w;
        rrow[12]=t3.x; rrow[13]=t3.y; rrow[14]=t3.z; rrow[15]=t3.w;
    }

    float4 q4 = *(const float4*)(bq + j0);
    float4 k4 = *(const float4*)(bk + j0);
    float4 v4 = *(const float4*)(bv + j0);
    #pragma unroll
    for (int k = 0; k < 16; ++k) {
        float rv = rrow[k];
        float4 wq4 = *(const float4*)(Wq + k * CURD + j0);
        float4 wk4 = *(const float4*)(Wk + k * CURD + j0);
        float4 wv4 = *(const float4*)(Wv + k * CURD + j0);
        q4.x = fmaf(rv, wq4.x, q4.x); q4.y = fmaf(rv, wq4.y, q4.y);
        q4.z = fmaf(rv, wq4.z, q4.z); q4.w = fmaf(rv, wq4.w, q4.w);
        k4.x = fmaf(rv, wk4.x, k4.x); k4.y = fmaf(rv, wk4.y, k4.y);
        k4.z = fmaf(rv, wk4.z, k4.z); k4.w = fmaf(rv, wk4.w, k4.w);
        v4.x = fmaf(rv, wv4.x, v4.x); v4.y = fmaf(rv, wv4.y, v4.y);
        v4.z = fmaf(rv, wv4.z, v4.z); v4.w = fmaf(rv, wv4.w, v4.w);
    }
    *(float4*)&Q[i][j0] = q4;
    *(float4*)&K[i][j0] = k4;
    *(float4*)&V[i][j0] = v4;

    float qrow[16];
    {
        float4 t0 = *(const float4*)&Q[i][0];
        float4 t1 = *(const float4*)&Q[i][4];
        float4 t2 = *(const float4*)&Q[i][8];
        float4 t3 = *(const float4*)&Q[i][12];
        qrow[0]=t0.x; qrow[1]=t0.y; qrow[2]=t0.z;  qrow[3]=t0.w;
        qrow[4]=t1.x; qrow[5]=t1.y; qrow[6]=t1.z;  qrow[7]=t1.w;
        qrow[8]=t2.x; qrow[9]=t2.y; qrow[10]=t2.z; qrow[11]=t2.w;
        qrow[12]=t3.x; qrow[13]=t3.y; qrow[14]=t3.z; qrow[15]=t3.w;
    }
    float sc[4];
    #pragma unroll
    for (int jj = 0; jj < 4; ++jj) {
        const int row = j0 + jj;
        float4 c0 = *(const float4*)&K[row][0];
        float4 c1 = *(const float4*)&K[row][4];
        float4 c2 = *(const float4*)&K[row][8];
        float4 c3 = *(const float4*)&K[row][12];
        float d0 = qrow[0]*c0.x + qrow[1]*c0.y + qrow[2]*c0.z + qrow[3]*c0.w;
        float d1 = qrow[4]*c1.x + qrow[5]*c1.y + qrow[6]*c1.z + qrow[7]*c1.w;
        float d2 = qrow[8]*c2.x + qrow[9]*c2.y + qrow[10]*c2.z + qrow[11]*c2.w;
        float d3 = qrow[12]*c3.x + qrow[13]*c3.y + qrow[14]*c3.z + qrow[15]*c3.w;
        sc[jj] = ((d0 + d1) + (d2 + d3)) * 0.25f;
    }

    float mx = fmaxf(fmaxf(sc[0], sc[1]), fmaxf(sc[2], sc[3]));
    mx = fmaxf(mx, __shfl_xor(mx, 1));
    mx = fmaxf(mx, __shfl_xor(mx, 2));
    float e0 = expf(sc[0]-mx), e1 = expf(sc[1]-mx),
          e2 = expf(sc[2]-mx), e3 = expf(sc[3]-mx);
    float es = (e0 + e1) + (e2 + e3);
    es += __shfl_xor(es, 1);
    es += __shfl_xor(es, 2);
    float rs = 1.f / es;
    float4 p4 = make_float4(e0*rs, e1*rs, e2*rs, e3*rs);
    *(float4*)&R[i][j0] = p4;

    float prow[16];
    {
        float4 t0 = *(const float4*)&R[i][0];
        float4 t1 = *(const float4*)&R[i][4];
        float4 t2 = *(const float4*)&R[i][8];
        float4 t3 = *(const float4*)&R[i][12];
        prow[0]=t0.x; prow[1]=t0.y; prow[2]=t0.z;  prow[3]=t0.w;
        prow[4]=t1.x; prow[5]=t1.y; prow[6]=t1.z;  prow[7]=t1.w;
        prow[8]=t2.x; prow[9]=t2.y; prow[10]=t2.z; prow[11]=t2.w;
        prow[12]=t3.x; prow[13]=t3.y; prow[14]=t3.z; prow[15]=t3.w;
    }
    float4 w4 = make_float4(0.f, 0.f, 0.f, 0.f);
    #pragma unroll
    for (int k = 0; k < 16; ++k) {
        float4 vk = *(const float4*)&V[k][j0];
        float pv = prow[k];
        w4.x = fmaf(pv, vk.x, w4.x); w4.y = fmaf(pv, vk.y, w4.y);
        w4.z = fmaf(pv, vk.z, w4.z); w4.w = fmaf(pv, vk.w, w4.w);
    }

    float s1 = (w4.x + w4.y) + (w4.z + w4.w);
    float s2 = (w4.x*w4.x + w4.y*w4.y) + (w4.z*w4.z + w4.w*w4.w);
    s1 += __shfl_xor(s1, 1); s1 += __shfl_xor(s1, 2);
    s2 += __shfl_xor(s2, 1); s2 += __shfl_xor(s2, 2);
    float m   = s1 * (1.f / 16.f);
    float var = s2 * (1.f / 16.f) - m * m;
    float inv = rsqrtf(var + LNEPS);
    float4 gl = *(const float4*)(g_lim + j0);
    float4 bl = *(const float4*)(b_lim + j0);
    float4 o;
    o.x = (w4.x - m) * inv * gl.x + bl.x;
    o.y = (w4.y - m) * inv * gl.y + bl.y;
    o.z = (w4.z - m) * inv * gl.z + bl.z;
    o.w = (w4.w - m) * inv * gl.w + bl.w;
    *(float4*)(combined + ((size_t)tile * CURD + i) * KDIM + j0) = o;

    // fold Wd packing into the first 192 blocks (completes before fused kernel)
    if (blockIdx.x < 192) {
        int idx = blockIdx.x * 256 + threadIdx.x;   // 0 .. 49151 = 96*512
        int k = idx / 512, c = idx % 512;
        float v = (k < KDIM) ? Wd[(size_t)k * OUTD + c] : 0.f;
        unsigned short h = f2bf(v);
        unsigned short l = f2bf(v - bf2f(h));
        int s = k >> 5, kk = k & 31, g = kk >> 3, e = kk & 7;
        size_t o2 = (((size_t)(s * 512 + c)) * 4 + g) * 8 + e;
        whi[o2] = h;
        wlo[o2] = l;
    }
}

// ---------------------------------------------------------------------------
// Kernel 2 (fused): producer rec chains + consumer out GEMM, flag-synced.
// v3: rec's ENTIRE watch trajectory (16 KB/chain) is preloaded to LDS before
// the loop — the serial chain performs ZERO global loads, so consumer memory
// traffic cannot inflate its latency. 2 chains per rec block (waves 0-1) keep
// the LDS union under the 64 KB static cap. Sync protocol unchanged from the
// round-4 version that passed.
// ---------------------------------------------------------------------------
union LdsU {
    struct {
        float watch[2][NCH][16];            // 32 KB
        float G[2][64];                     // 512 B
    } rec;
    struct {
        unsigned short Ahi[32][104];        // 6.5 KB
        unsigned short Alo[32][104];        // 6.5 KB
        float red[4][32][2];                // 1 KB
    } o;
};

__global__ __launch_bounds__(256, 1) void fused_kernel(
    const float* __restrict__ Ws, const float* __restrict__ bs,
    const float* __restrict__ g_doubt, const float* __restrict__ b_doubt,
    float* __restrict__ combined,
    const unsigned short* __restrict__ Bhi,
    const unsigned short* __restrict__ Blo,
    const float* __restrict__ bd, const float* __restrict__ g_check,
    const float* __restrict__ b_check, float* __restrict__ out,
    unsigned int* __restrict__ flags)
{
    __shared__ __align__(16) LdsU lds;
    __shared__ int s_tk;

    const int tid = threadIdx.x;
    if (tid == 0)
        s_tk = (int)__hip_atomic_fetch_add(&flags[0], 1u,
                    __ATOMIC_RELAXED, __HIP_MEMORY_SCOPE_AGENT);
    __syncthreads();
    const int role_tk = s_tk;

    if (role_tk < NRECB) {
        // ---------------- rec role: 2 chains (waves 0-1) ----------------
        const int wid = tid >> 6;
        if (wid >= 2) return;               // waves 2,3 idle out
        __builtin_amdgcn_s_setprio(1);
        const int c   = tid & 63;
        const int lane = c;
        const int chain = role_tk * 2 + wid;
        const int b = chain >> 4;
        const int r = chain & 15;

        // ---- preload this chain's full watch trajectory into LDS ----
        {
            const int tt4 = lane >> 2;      // chunk-within-pass
            const int j4  = lane & 3;       // float4 index in row
            #pragma unroll
            for (int p = 0; p < 16; ++p) {
                int t = p * 16 + tt4;
                float4 v = *(const float4*)(combined
                    + ((size_t)(t * BB + b) * CURD + r) * KDIM + j4 * 4);
                *(float4*)&lds.rec.watch[wid][t][j4 * 4] = v;
            }
        }

        float Wsw[16];
        #pragma unroll
        for (int j = 0; j < 16; ++j) Wsw[j] = Ws[j * HIDD + c];

        float Wsp[64];
        float u = 0.f, w0 = 0.f;
        #pragma unroll
        for (int j = 0; j < 64; ++j) {
            float w   = Ws[(16 + j) * HIDD + c];
            float gdj = g_doubt[j];
            float bdj = b_doubt[j];
            Wsp[j] = gdj * w;
            u += Wsp[j];
            w0 = fmaf(bdj, w, w0);
        }
        const float bsc  = bs[c];
        const float gd_c = g_doubt[c];
        const float bd_c = b_doubt[c];

        size_t rowoff = ((size_t)b * CURD + r) * KDIM;
        const size_t stride = (size_t)BB * CURD * KDIM;

        // wave-local: LDS writes above are in-order with the reads below
        const float4* wrow0 = (const float4*)&lds.rec.watch[wid][0][0];
        float4 wc0 = wrow0[0], wc1 = wrow0[1], wc2 = wrow0[2], wc3 = wrow0[3];

        float P = 0.f, mp = 0.f, ip = 0.f, w0f = 0.f;
        float sv_store = 0.f;

        for (int t = 0; t < NCH; ++t) {
            // fire-and-forget write-through store (visible at coherent point)
            __hip_atomic_store(&combined[rowoff + 16 + c], sv_store,
                               __ATOMIC_RELAXED, __HIP_MEMORY_SCOPE_AGENT);

            // slab signal: every 16 chunks; vmcnt(0) drains only sus stores
            if ((t & 15) == 15) {
                asm volatile("s_waitcnt vmcnt(0)" ::: "memory");
                if (c == 0)
                    __hip_atomic_fetch_add(&flags[16 + (t >> 4) * 16], 1u,
                        __ATOMIC_RELAXED, __HIP_MEMORY_SCOPE_AGENT);
            }

            float h0 = fmaf(ip, P - mp * u, bsc + w0f);
            float h1 = 0.f, h2 = 0.f, h3 = 0.f;
            h0 = fmaf(wc0.x, Wsw[0],  h0); h1 = fmaf(wc0.y, Wsw[1],  h1);
            h2 = fmaf(wc0.z, Wsw[2],  h2); h3 = fmaf(wc0.w, Wsw[3],  h3);
            h0 = fmaf(wc1.x, Wsw[4],  h0); h1 = fmaf(wc1.y, Wsw[5],  h1);
            h2 = fmaf(wc1.z, Wsw[6],  h2); h3 = fmaf(wc1.w, Wsw[7],  h3);
            h0 = fmaf(wc2.x, Wsw[8],  h0); h1 = fmaf(wc2.y, Wsw[9],  h1);
            h2 = fmaf(wc2.z, Wsw[10], h2); h3 = fmaf(wc2.w, Wsw[11], h3);
            h0 = fmaf(wc3.x, Wsw[12], h0); h1 = fmaf(wc3.y, Wsw[13], h1);
            h2 = fmaf(wc3.z, Wsw[14], h2); h3 = fmaf(wc3.w, Wsw[15], h3);
            float h = (h0 + h1) + (h2 + h3);

            float G = 0.5f * h * (1.f + erff(h * 0.70710678118654752f));

            lds.rec.G[wid][c] = G;
            const float4* gp = (const float4*)lds.rec.G[wid];

            // prefetch next chunk's watch from LDS (overlaps reduce + matvec)
            const int tn = (t + 1 < NCH) ? t + 1 : t;
            const float4* wrow = (const float4*)&lds.rec.watch[wid][tn][0];
            float4 wn0 = wrow[0], wn1 = wrow[1], wn2 = wrow[2], wn3 = wrow[3];

            float s1 = wave64_sum(G);
            float s2 = wave64_sum(G * G);
            float m   = s1 * (1.f / 64.f);
            float var = s2 * (1.f / 64.f) - m * m;
            float inv = rsqrtf(var + LNEPS);

            // P = sum_j G_j * Wsp_j — batched 4x4 float4 to cap live regs
            float p0=0.f,p1=0.f,p2=0.f,p3=0.f,p4=0.f,p5=0.f,p6=0.f,p7=0.f;
            #pragma unroll
            for (int bq = 0; bq < 4; ++bq) {
                float4 x0 = gp[bq*4+0], x1 = gp[bq*4+1];
                float4 x2 = gp[bq*4+2], x3 = gp[bq*4+3];
                p0 = fmaf(x0.x, Wsp[16*bq+0],  p0);
                p1 = fmaf(x0.y, Wsp[16*bq+1],  p1);
                p2 = fmaf(x0.z, Wsp[16*bq+2],  p2);
                p3 = fmaf(x0.w, Wsp[16*bq+3],  p3);
                p4 = fmaf(x1.x, Wsp[16*bq+4],  p4);
                p5 = fmaf(x1.y, Wsp[16*bq+5],  p5);
                p6 = fmaf(x1.z, Wsp[16*bq+6],  p6);
                p7 = fmaf(x1.w, Wsp[16*bq+7],  p7);
                p0 = fmaf(x2.x, Wsp[16*bq+8],  p0);
                p1 = fmaf(x2.y, Wsp[16*bq+9],  p1);
                p2 = fmaf(x2.z, Wsp[16*bq+10], p2);
                p3 = fmaf(x2.w, Wsp[16*bq+11], p3);
                p4 = fmaf(x3.x, Wsp[16*bq+12], p4);
                p5 = fmaf(x3.y, Wsp[16*bq+13], p5);
                p6 = fmaf(x3.z, Wsp[16*bq+14], p6);
                p7 = fmaf(x3.w, Wsp[16*bq+15], p7);
            }
            P = ((p0 + p1) + (p2 + p3)) + ((p4 + p5) + (p6 + p7));

            sv_store = fmaf((G - m) * inv, gd_c, bd_c);
            mp = m; ip = inv; w0f = w0;
            wc0 = wn0; wc1 = wn1; wc2 = wn2; wc3 = wn3;
            rowoff += stride;
        }
        return;
    }

    // ---------------- out role: task loop over 32-row tiles ----------------
    const int lane  = tid & 63;
    const int wid   = tid >> 6;
    const int arowb = lane & 15;
    const int kg    = lane >> 4;

    int cols[8]; float bdv[8], gcv[8], bcv[8];
    #pragma unroll
    for (int n = 0; n < 8; ++n) {
        cols[n] = wid * 128 + n * 16 + arowb;
        bdv[n] = bd[cols[n]];
        gcv[n] = g_check[cols[n]];
        bcv[n] = b_check[cols[n]];
    }

    for (;;) {
        if (tid == 0)
            s_tk = (int)__hip_atomic_fetch_add(&flags[1], 1u,
                        __ATOMIC_RELAXED, __HIP_MEMORY_SCOPE_AGENT);
        __syncthreads();
        const int task = s_tk;
        if (task >= NTASKS) break;

        const int slab = task >> 8;    // 256 tasks per 16-chunk slab
        if (tid == 0) {
            unsigned guard = 0;
            while (__hip_atomic_load(&flags[16 + slab * 16], __ATOMIC_RELAXED,
                                     __HIP_MEMORY_SCOPE_AGENT) < 512u
                   && guard < (1u << 20)) {
                __builtin_amdgcn_s_sleep(32);
                ++guard;
            }
        }
        __syncthreads();
        asm volatile("" ::: "memory");   // compiler barrier (no cache ops)

        const size_t rowbase = (size_t)task * 32;

        // stage + split-convert A (32 rows x 80), zero-pad k in [80,96)
        {
            const float4* src4 = (const float4*)(combined + rowbase * KDIM);
            #pragma unroll
            for (int u2 = 0; u2 < 3; ++u2) {
                int idx = tid + 256 * u2;
                if (idx < 32 * 20) {
                    float4 v = src4[idx];
                    int rr = idx / 20, k4 = idx % 20;
                    float vs[4] = {v.x, v.y, v.z, v.w};
                    #pragma unroll
                    for (int e = 0; e < 4; ++e) {
                        unsigned short h = f2bf(vs[e]);
                        lds.o.Ahi[rr][k4 * 4 + e] = h;
                        lds.o.Alo[rr][k4 * 4 + e] = f2bf(vs[e] - bf2f(h));
                    }
                }
            }
            #pragma unroll
            for (int u2 = 0; u2 < 2; ++u2) {
                int idx = tid + 256 * u2;
                int rr = idx >> 4, kk = 80 + (idx & 15);
                lds.o.Ahi[rr][kk] = 0;
                lds.o.Alo[rr][kk] = 0;
            }
        }
        __syncthreads();

        bf16x8 a_hi[2][3], a_lo[2][3];
        #pragma unroll
        for (int ms = 0; ms < 2; ++ms)
            #pragma unroll
            for (int s = 0; s < 3; ++s) {
                a_hi[ms][s] = *(const bf16x8*)&lds.o.Ahi[ms * 16 + arowb][s * 32 + kg * 8];
                a_lo[ms][s] = *(const bf16x8*)&lds.o.Alo[ms * 16 + arowb][s * 32 + kg * 8];
            }

        f32x4 acc[2][8];
        #pragma unroll
        for (int ms = 0; ms < 2; ++ms)
            #pragma unroll
            for (int n = 0; n < 8; ++n) acc[ms][n] = (f32x4){0.f, 0.f, 0.f, 0.f};

        #pragma unroll
        for (int n = 0; n < 8; ++n) {
            #pragma unroll
            for (int s = 0; s < 3; ++s) {
                size_t off = (((size_t)(s * 512 + cols[n])) * 4 + kg) * 8;
                bf16x8 bh = *(const bf16x8*)(Bhi + off);
                bf16x8 bl = *(const bf16x8*)(Blo + off);
                acc[0][n] = __builtin_amdgcn_mfma_f32_16x16x32_bf16(a_hi[0][s], bh, acc[0][n], 0, 0, 0);
                acc[1][n] = __builtin_amdgcn_mfma_f32_16x16x32_bf16(a_hi[1][s], bh, acc[1][n], 0, 0, 0);
                acc[0][n] = __builtin_amdgcn_mfma_f32_16x16x32_bf16(a_lo[0][s], bh, acc[0][n], 0, 0, 0);
                acc[1][n] = __builtin_amdgcn_mfma_f32_16x16x32_bf16(a_lo[1][s], bh, acc[1][n], 0, 0, 0);
                acc[0][n] = __builtin_amdgcn_mfma_f32_16x16x32_bf16(a_hi[0][s], bl, acc[0][n], 0, 0, 0);
                acc[1][n] = __builtin_amdgcn_mfma_f32_16x16x32_bf16(a_hi[1][s], bl, acc[1][n], 0, 0, 0);
            }
        }

        #pragma unroll
        for (int ms = 0; ms < 2; ++ms) {
            float s1[4] = {0.f, 0.f, 0.f, 0.f};
            float s2[4] = {0.f, 0.f, 0.f, 0.f};
            #pragma unroll
            for (int n = 0; n < 8; ++n) {
                #pragma unroll
                for (int j = 0; j < 4; ++j) {
                    float v = acc[ms][n][j] + bdv[n];
                    acc[ms][n][j] = v;
                    s1[j] += v;
                    s2[j] = fmaf(v, v, s2[j]);
                }
            }
            #pragma unroll
            for (int j = 0; j < 4; ++j) {
                s1[j] = row16_sum(s1[j]);
                s2[j] = row16_sum(s2[j]);
            }
            if (arowb == 0) {
                #pragma unroll
                for (int j = 0; j < 4; ++j) {
                    lds.o.red[wid][ms * 16 + kg * 4 + j][0] = s1[j];
                    lds.o.red[wid][ms * 16 + kg * 4 + j][1] = s2[j];
                }
            }
        }
        __syncthreads();

        #pragma unroll
        for (int ms = 0; ms < 2; ++ms) {
            #pragma unroll
            for (int j = 0; j < 4; ++j) {
                const int rowl = ms * 16 + kg * 4 + j;
                float t1 = (lds.o.red[0][rowl][0] + lds.o.red[1][rowl][0])
                         + (lds.o.red[2][rowl][0] + lds.o.red[3][rowl][0]);
                float t2 = (lds.o.red[0][rowl][1] + lds.o.red[1][rowl][1])
                         + (lds.o.red[2][rowl][1] + lds.o.red[3][rowl][1]);
                float mm  = t1 * (1.f / 512.f);
                float var = t2 * (1.f / 512.f) - mm * mm;
                float iv  = rsqrtf(var + LNEPS);

                size_t R = rowbase + (size_t)rowl;
                int ii  = (int)(R & 15);
                int bb2 = (int)((R >> 4) & 31);
                int tt  = (int)(R >> 9);
                size_t orow = ((size_t)bb2 * SS + (size_t)tt * CURD + ii) * OUTD;

                #pragma unroll
                for (int n = 0; n < 8; ++n) {
                    out[orow + cols[n]] =
                        (acc[ms][n][j] - mm) * iv * gcv[n] + bcv[n];
                }
            }
        }
        __syncthreads();
    }
}

// ---------------------------------------------------------------------------
extern "C" void kernel_launch(void* const* d_in, const int* in_sizes, int n_in,
                              void* d_out, int out_size, void* d_ws, size_t ws_size,
                              hipStream_t stream)
{
    const int*   x       = (const int*)  d_in[0];
    const float* emb     = (const float*)d_in[1];
    const float* Wq      = (const float*)d_in[2];
    const float* bq      = (const float*)d_in[3];
    const float* Wk      = (const float*)d_in[4];
    const float* bk      = (const float*)d_in[5];
    const float* Wv      = (const float*)d_in[6];
    const float* bv      = (const float*)d_in[7];
    const float* g_lim   = (const float*)d_in[8];
    const float* b_lim   = (const float*)d_in[9];
    const float* Ws      = (const float*)d_in[10];
    const float* bs      = (const float*)d_in[11];
    const float* g_doubt = (const float*)d_in[12];
    const float* b_doubt = (const float*)d_in[13];
    const float* Wd      = (const float*)d_in[14];
    const float* bd      = (const float*)d_in[15];
    const float* g_check = (const float*)d_in[16];
    const float* b_check = (const float*)d_in[17];

    float* out      = (float*)d_out;
    float* combined = (float*)d_ws;    // [NCH][BB][CURD][KDIM] fp32 = 40 MB
    unsigned short* whi = (unsigned short*)((char*)d_ws + WS_WHI);
    unsigned short* wlo = (unsigned short*)((char*)d_ws + WS_WLO);
    unsigned int*  flags = (unsigned int*)((char*)d_ws + WS_FLAGS);

    attn_kernel<<<dim3(NCH * BB / 4), dim3(256), 0, stream>>>(
        x, emb, Wq, bq, Wk, bk, Wv, bv, g_lim, b_lim, combined,
        Wd, whi, wlo, flags);

    fused_kernel<<<dim3(NRECB + NOUTB), dim3(256), 0, stream>>>(
        Ws, bs, g_doubt, b_doubt, combined, whi, wlo,
        bd, g_check, b_check, out, flags);
}

// Round 6
// 509.463 us; speedup vs baseline: 1.5275x; 1.0851x over previous
//
#include <hip/hip_runtime.h>
#include <math.h>

#define VOCN 50257
#define OUTD 512
#define HIDD 64
#define CURD 16
#define BB   32
#define SS   4096
#define NCH  256      // SS / CURD
#define KDIM 80       // HIDD + CURD
#define LNEPS 1e-5f

// workspace layout
#define WS_WHI   41943040                  // combined = [0, 40MB)
#define WS_WLO   (WS_WHI + 96*512*2)

// ---------------------------------------------------------------------------
// helpers
// ---------------------------------------------------------------------------
#define DPP_ADD(x, ctrl) \
    ((x) + __int_as_float(__builtin_amdgcn_update_dpp( \
        0, __float_as_int(x), (ctrl), 0xf, 0xf, true)))

__device__ __forceinline__ float row16_sum(float x) {
    x = DPP_ADD(x, 0xB1);   // quad_perm xor1
    x = DPP_ADD(x, 0x4E);   // quad_perm xor2
    x = DPP_ADD(x, 0x141);  // row_half_mirror xor4
    x = DPP_ADD(x, 0x140);  // row_mirror xor8
    return x;
}

__device__ __forceinline__ float wave64_sum(float x) {
    float r = row16_sum(x);
    float a = __int_as_float(__builtin_amdgcn_readlane(__float_as_int(r), 0));
    float b = __int_as_float(__builtin_amdgcn_readlane(__float_as_int(r), 16));
    float c = __int_as_float(__builtin_amdgcn_readlane(__float_as_int(r), 32));
    float d = __int_as_float(__builtin_amdgcn_readlane(__float_as_int(r), 48));
    return (a + b) + (c + d);
}

__device__ __forceinline__ unsigned short f2bf(float x) {
    unsigned u = __float_as_uint(x);
    u += 0x7fffu + ((u >> 16) & 1u);
    return (unsigned short)(u >> 16);
}
__device__ __forceinline__ float bf2f(unsigned short h) {
    return __uint_as_float(((unsigned)h) << 16);
}

typedef __attribute__((ext_vector_type(8))) short bf16x8;
typedef __attribute__((ext_vector_type(4))) float f32x4;

// ---------------------------------------------------------------------------
// Kernel 1: attention, ONE WAVE per (t,b) tile + Wd packing folded in.
// ---------------------------------------------------------------------------
__global__ __launch_bounds__(256) void attn_kernel(
    const int* __restrict__ x, const float* __restrict__ emb,
    const float* __restrict__ Wq, const float* __restrict__ bq,
    const float* __restrict__ Wk, const float* __restrict__ bk,
    const float* __restrict__ Wv, const float* __restrict__ bv,
    const float* __restrict__ g_lim, const float* __restrict__ b_lim,
    float* __restrict__ combined,
    const float* __restrict__ Wd,
    unsigned short* __restrict__ whi, unsigned short* __restrict__ wlo)
{
    const int wid  = threadIdx.x >> 6;
    const int lane = threadIdx.x & 63;
    const int tile = blockIdx.x * 4 + wid;
    const int t = tile >> 5, b = tile & 31;
    const int i  = lane >> 2;
    const int jg = lane & 3;
    const int j0 = jg * 4;

    __shared__ __align__(16) float ldsT[4][4][16][20];
    float (*R)[20] = ldsT[wid][0];
    float (*Q)[20] = ldsT[wid][1];
    float (*K)[20] = ldsT[wid][2];
    float (*V)[20] = ldsT[wid][3];

    int myid = 0;
    if (lane < 16) myid = x[b * SS + t * CURD + lane];
    const int id_i = __shfl(myid, i, 64);

    float4 r4 = *(const float4*)(emb + (size_t)id_i * CURD + j0);
    *(float4*)&R[i][j0] = r4;

    float rrow[16];
    {
        float4 t0 = *(const float4*)&R[i][0];
        float4 t1 = *(const float4*)&R[i][4];
        float4 t2 = *(const float4*)&R[i][8];
        float4 t3 = *(const float4*)&R[i][12];
        rrow[0]=t0.x; rrow[1]=t0.y; rrow[2]=t0.z;  rrow[3]=t0.w;
        rrow[4]=t1.x; rrow[5]=t1.y; rrow[6]=t1.z;  rrow[7]=t1.w;
        rrow[8]=t2.x; rrow[9]=t2.y; rrow[10]=t2.z; rrow[11]=t2.w;
        rrow[12]=t3.x; rrow[13]=t3.y; rrow[14]=t3.z; rrow[15]=t3.w;
    }

    float4 q4 = *(const float4*)(bq + j0);
    float4 k4 = *(const float4*)(bk + j0);
    float4 v4 = *(const float4*)(bv + j0);
    #pragma unroll
    for (int k = 0; k < 16; ++k) {
        float rv = rrow[k];
        float4 wq4 = *(const float4*)(Wq + k * CURD + j0);
        float4 wk4 = *(const float4*)(Wk + k * CURD + j0);
        float4 wv4 = *(const float4*)(Wv + k * CURD + j0);
        q4.x = fmaf(rv, wq4.x, q4.x); q4.y = fmaf(rv, wq4.y, q4.y);
        q4.z = fmaf(rv, wq4.z, q4.z); q4.w = fmaf(rv, wq4.w, q4.w);
        k4.x = fmaf(rv, wk4.x, k4.x); k4.y = fmaf(rv, wk4.y, k4.y);
        k4.z = fmaf(rv, wk4.z, k4.z); k4.w = fmaf(rv, wk4.w, k4.w);
        v4.x = fmaf(rv, wv4.x, v4.x); v4.y = fmaf(rv, wv4.y, v4.y);
        v4.z = fmaf(rv, wv4.z, v4.z); v4.w = fmaf(rv, wv4.w, v4.w);
    }
    *(float4*)&Q[i][j0] = q4;
    *(float4*)&K[i][j0] = k4;
    *(float4*)&V[i][j0] = v4;

    float qrow[16];
    {
        float4 t0 = *(const float4*)&Q[i][0];
        float4 t1 = *(const float4*)&Q[i][4];
        float4 t2 = *(const float4*)&Q[i][8];
        float4 t3 = *(const float4*)&Q[i][12];
        qrow[0]=t0.x; qrow[1]=t0.y; qrow[2]=t0.z;  qrow[3]=t0.w;
        qrow[4]=t1.x; qrow[5]=t1.y; qrow[6]=t1.z;  qrow[7]=t1.w;
        qrow[8]=t2.x; qrow[9]=t2.y; qrow[10]=t2.z; qrow[11]=t2.w;
        qrow[12]=t3.x; qrow[13]=t3.y; qrow[14]=t3.z; qrow[15]=t3.w;
    }
    float sc[4];
    #pragma unroll
    for (int jj = 0; jj < 4; ++jj) {
        const int row = j0 + jj;
        float4 c0 = *(const float4*)&K[row][0];
        float4 c1 = *(const float4*)&K[row][4];
        float4 c2 = *(const float4*)&K[row][8];
        float4 c3 = *(const float4*)&K[row][12];
        float d0 = qrow[0]*c0.x + qrow[1]*c0.y + qrow[2]*c0.z + qrow[3]*c0.w;
        float d1 = qrow[4]*c1.x + qrow[5]*c1.y + qrow[6]*c1.z + qrow[7]*c1.w;
        float d2 = qrow[8]*c2.x + qrow[9]*c2.y + qrow[10]*c2.z + qrow[11]*c2.w;
        float d3 = qrow[12]*c3.x + qrow[13]*c3.y + qrow[14]*c3.z + qrow[15]*c3.w;
        sc[jj] = ((d0 + d1) + (d2 + d3)) * 0.25f;
    }

    float mx = fmaxf(fmaxf(sc[0], sc[1]), fmaxf(sc[2], sc[3]));
    mx = fmaxf(mx, __shfl_xor(mx, 1));
    mx = fmaxf(mx, __shfl_xor(mx, 2));
    float e0 = expf(sc[0]-mx), e1 = expf(sc[1]-mx),
          e2 = expf(sc[2]-mx), e3 = expf(sc[3]-mx);
    float es = (e0 + e1) + (e2 + e3);
    es += __shfl_xor(es, 1);
    es += __shfl_xor(es, 2);
    float rs = 1.f / es;
    float4 p4 = make_float4(e0*rs, e1*rs, e2*rs, e3*rs);
    *(float4*)&R[i][j0] = p4;

    float prow[16];
    {
        float4 t0 = *(const float4*)&R[i][0];
        float4 t1 = *(const float4*)&R[i][4];
        float4 t2 = *(const float4*)&R[i][8];
        float4 t3 = *(const float4*)&R[i][12];
        prow[0]=t0.x; prow[1]=t0.y; prow[2]=t0.z;  prow[3]=t0.w;
        prow[4]=t1.x; prow[5]=t1.y; prow[6]=t1.z;  prow[7]=t1.w;
        prow[8]=t2.x; prow[9]=t2.y; prow[10]=t2.z; prow[11]=t2.w;
        prow[12]=t3.x; prow[13]=t3.y; prow[14]=t3.z; prow[15]=t3.w;
    }
    float4 w4 = make_float4(0.f, 0.f, 0.f, 0.f);
    #pragma unroll
    for (int k = 0; k < 16; ++k) {
        float4 vk = *(const float4*)&V[k][j0];
        float pv = prow[k];
        w4.x = fmaf(pv, vk.x, w4.x); w4.y = fmaf(pv, vk.y, w4.y);
        w4.z = fmaf(pv, vk.z, w4.z); w4.w = fmaf(pv, vk.w, w4.w);
    }

    float s1 = (w4.x + w4.y) + (w4.z + w4.w);
    float s2 = (w4.x*w4.x + w4.y*w4.y) + (w4.z*w4.z + w4.w*w4.w);
    s1 += __shfl_xor(s1, 1); s1 += __shfl_xor(s1, 2);
    s2 += __shfl_xor(s2, 1); s2 += __shfl_xor(s2, 2);
    float m   = s1 * (1.f / 16.f);
    float var = s2 * (1.f / 16.f) - m * m;
    float inv = rsqrtf(var + LNEPS);
    float4 gl = *(const float4*)(g_lim + j0);
    float4 bl = *(const float4*)(b_lim + j0);
    float4 o;
    o.x = (w4.x - m) * inv * gl.x + bl.x;
    o.y = (w4.y - m) * inv * gl.y + bl.y;
    o.z = (w4.z - m) * inv * gl.z + bl.z;
    o.w = (w4.w - m) * inv * gl.w + bl.w;
    *(float4*)(combined + ((size_t)tile * CURD + i) * KDIM + j0) = o;

    // fold Wd packing into the first 192 blocks
    if (blockIdx.x < 192) {
        int idx = blockIdx.x * 256 + threadIdx.x;   // 0 .. 49151 = 96*512
        int k = idx / 512, c = idx % 512;
        float v = (k < KDIM) ? Wd[(size_t)k * OUTD + c] : 0.f;
        unsigned short h = f2bf(v);
        unsigned short l = f2bf(v - bf2f(h));
        int s = k >> 5, kk = k & 31, g = kk >> 3, e = kk & 7;
        size_t o2 = (((size_t)(s * 512 + c)) * 4 + g) * 8 + e;
        whi[o2] = h;
        wlo[o2] = l;
    }
}

// ---------------------------------------------------------------------------
// Kernel 2 (standalone rec, LDS-watch): 512 chains; 256 blocks x 128 threads
// (2 waves = 2 chains each). The chain's full watch trajectory (16 KB) is
// preloaded to LDS; the serial loop has ZERO global loads, plain fire-and-
// forget sus stores, no flags/fences/atomics. Watch-part of h(t+1) is
// computed while the G all-gather LDS reads are in flight.
// ---------------------------------------------------------------------------
__global__ __launch_bounds__(128) void rec_kernel(
    const float* __restrict__ Ws, const float* __restrict__ bs,
    const float* __restrict__ g_doubt, const float* __restrict__ b_doubt,
    float* __restrict__ combined)
{
    __shared__ __align__(16) float s_watch[2][NCH][16];   // 32 KB
    __shared__ __align__(16) float s_G[2][64];

    const int wid = threadIdx.x >> 6;
    const int c   = threadIdx.x & 63;
    const int chain = blockIdx.x * 2 + wid;
    const int b = chain >> 4;
    const int r = chain & 15;

    // ---- preload this chain's full watch trajectory into LDS (wave-local) --
    {
        const int tt4 = c >> 2;             // 16 chunks per pass
        const int j4  = c & 3;              // float4 index in row
        #pragma unroll
        for (int p = 0; p < 16; ++p) {
            int t = p * 16 + tt4;
            float4 v = *(const float4*)(combined
                + ((size_t)(t * BB + b) * CURD + r) * KDIM + j4 * 4);
            *(float4*)&s_watch[wid][t][j4 * 4] = v;
        }
    }

    float Wsw[16];
    #pragma unroll
    for (int j = 0; j < 16; ++j) Wsw[j] = Ws[j * HIDD + c];

    float Wsp[64];
    float u = 0.f, w0 = 0.f;
    #pragma unroll
    for (int j = 0; j < 64; ++j) {
        float w   = Ws[(16 + j) * HIDD + c];
        float gdj = g_doubt[j];
        float bdj = b_doubt[j];
        Wsp[j] = gdj * w;
        u += Wsp[j];
        w0 = fmaf(bdj, w, w0);
    }
    const float bsc  = bs[c];
    const float gd_c = g_doubt[c];
    const float bd_c = b_doubt[c];

    size_t rowoff = ((size_t)b * CURD + r) * KDIM;
    const size_t stride = (size_t)BB * CURD * KDIM;

    // watch-part for t=0 (wave-local LDS: writes above are in-order)
    float wp0, wp1, wp2, wp3;
    {
        const float4* wrow = (const float4*)&s_watch[wid][0][0];
        float4 a0 = wrow[0], a1 = wrow[1], a2 = wrow[2], a3 = wrow[3];
        wp0 = a0.x*Wsw[0]; wp1 = a0.y*Wsw[1]; wp2 = a0.z*Wsw[2]; wp3 = a0.w*Wsw[3];
        wp0 = fmaf(a1.x, Wsw[4],  wp0); wp1 = fmaf(a1.y, Wsw[5],  wp1);
        wp2 = fmaf(a1.z, Wsw[6],  wp2); wp3 = fmaf(a1.w, Wsw[7],  wp3);
        wp0 = fmaf(a2.x, Wsw[8],  wp0); wp1 = fmaf(a2.y, Wsw[9],  wp1);
        wp2 = fmaf(a2.z, Wsw[10], wp2); wp3 = fmaf(a2.w, Wsw[11], wp3);
        wp0 = fmaf(a3.x, Wsw[12], wp0); wp1 = fmaf(a3.y, Wsw[13], wp1);
        wp2 = fmaf(a3.z, Wsw[14], wp2); wp3 = fmaf(a3.w, Wsw[15], wp3);
    }

    float P = 0.f, mp = 0.f, ip = 0.f, w0f = 0.f;
    float sv_store = 0.f;

    for (int t = 0; t < NCH; ++t) {
        // sus entering chunk t (fire-and-forget; kernel boundary = coherence)
        combined[rowoff + 16 + c] = sv_store;

        float h = (fmaf(ip, P - mp * u, bsc + w0f) + wp0)
                + ((wp1 + wp2) + wp3);

        float G = 0.5f * h * (1.f + erff(h * 0.70710678118654752f));

        // all-gather G via LDS
        s_G[wid][c] = G;
        const float4* gp = (const float4*)s_G[wid];

        // watch-part for t+1 — overlaps the ds_read latency of gp
        {
            const int tn = (t + 1 < NCH) ? t + 1 : t;
            const float4* wrow = (const float4*)&s_watch[wid][tn][0];
            float4 a0 = wrow[0], a1 = wrow[1], a2 = wrow[2], a3 = wrow[3];
            wp0 = a0.x*Wsw[0]; wp1 = a0.y*Wsw[1]; wp2 = a0.z*Wsw[2]; wp3 = a0.w*Wsw[3];
            wp0 = fmaf(a1.x, Wsw[4],  wp0); wp1 = fmaf(a1.y, Wsw[5],  wp1);
            wp2 = fmaf(a1.z, Wsw[6],  wp2); wp3 = fmaf(a1.w, Wsw[7],  wp3);
            wp0 = fmaf(a2.x, Wsw[8],  wp0); wp1 = fmaf(a2.y, Wsw[9],  wp1);
            wp2 = fmaf(a2.z, Wsw[10], wp2); wp3 = fmaf(a2.w, Wsw[11], wp3);
            wp0 = fmaf(a3.x, Wsw[12], wp0); wp1 = fmaf(a3.y, Wsw[13], wp1);
            wp2 = fmaf(a3.z, Wsw[14], wp2); wp3 = fmaf(a3.w, Wsw[15], wp3);
        }

        // (m, inv) reduce — pure VALU DPP, overlaps LDS reads too
        float s1 = wave64_sum(G);
        float s2 = wave64_sum(G * G);
        float m   = s1 * (1.f / 64.f);
        float var = s2 * (1.f / 64.f) - m * m;
        float inv = rsqrtf(var + LNEPS);

        // P = sum_j G_j * Wsp_j   (8 accumulators, batched float4 reads)
        float p0=0.f,p1=0.f,p2=0.f,p3=0.f,p4=0.f,p5=0.f,p6=0.f,p7=0.f;
        #pragma unroll
        for (int bq = 0; bq < 4; ++bq) {
            float4 x0 = gp[bq*4+0], x1 = gp[bq*4+1];
            float4 x2 = gp[bq*4+2], x3 = gp[bq*4+3];
            p0 = fmaf(x0.x, Wsp[16*bq+0],  p0);
            p1 = fmaf(x0.y, Wsp[16*bq+1],  p1);
            p2 = fmaf(x0.z, Wsp[16*bq+2],  p2);
            p3 = fmaf(x0.w, Wsp[16*bq+3],  p3);
            p4 = fmaf(x1.x, Wsp[16*bq+4],  p4);
            p5 = fmaf(x1.y, Wsp[16*bq+5],  p5);
            p6 = fmaf(x1.z, Wsp[16*bq+6],  p6);
            p7 = fmaf(x1.w, Wsp[16*bq+7],  p7);
            p0 = fmaf(x2.x, Wsp[16*bq+8],  p0);
            p1 = fmaf(x2.y, Wsp[16*bq+9],  p1);
            p2 = fmaf(x2.z, Wsp[16*bq+10], p2);
            p3 = fmaf(x2.w, Wsp[16*bq+11], p3);
            p4 = fmaf(x3.x, Wsp[16*bq+12], p4);
            p5 = fmaf(x3.y, Wsp[16*bq+13], p5);
            p6 = fmaf(x3.z, Wsp[16*bq+14], p6);
            p7 = fmaf(x3.w, Wsp[16*bq+15], p7);
        }
        P = ((p0 + p1) + (p2 + p3)) + ((p4 + p5) + (p6 + p7));

        sv_store = fmaf((G - m) * inv, gd_c, bd_c);
        mp = m; ip = inv; w0f = w0;
        rowoff += stride;
    }
}

// ---------------------------------------------------------------------------
// Kernel 3: out = LN(combined @ Wd + bd) * g_check + b_check  (split-bf16
// MFMA; proven R1 version).
// ---------------------------------------------------------------------------
#define M_BLK 32
__global__ __launch_bounds__(256) void out_mfma_kernel(
    const float* __restrict__ combined,
    const unsigned short* __restrict__ Bhi,
    const unsigned short* __restrict__ Blo,
    const float* __restrict__ bd, const float* __restrict__ g_check,
    const float* __restrict__ b_check, float* __restrict__ out)
{
    __shared__ __align__(16) unsigned short Ahi[M_BLK][104];
    __shared__ __align__(16) unsigned short Alo[M_BLK][104];
    __shared__ float red[4][M_BLK][2];

    const int tid = threadIdx.x;
    const size_t rowbase = (size_t)blockIdx.x * M_BLK;

    {
        const float4* src4 = (const float4*)(combined + rowbase * KDIM);
        #pragma unroll
        for (int u2 = 0; u2 < 3; ++u2) {
            int idx = tid + 256 * u2;
            if (idx < M_BLK * 20) {
                float4 v = src4[idx];
                int rr = idx / 20, k4 = idx % 20;
                float vs[4] = {v.x, v.y, v.z, v.w};
                #pragma unroll
                for (int e = 0; e < 4; ++e) {
                    unsigned short h = f2bf(vs[e]);
                    Ahi[rr][k4 * 4 + e] = h;
                    Alo[rr][k4 * 4 + e] = f2bf(vs[e] - bf2f(h));
                }
            }
        }
        #pragma unroll
        for (int u2 = 0; u2 < 2; ++u2) {
            int idx = tid + 256 * u2;
            int rr = idx >> 4, kk = 80 + (idx & 15);
            Ahi[rr][kk] = 0;
            Alo[rr][kk] = 0;
        }
    }

    const int lane  = tid & 63;
    const int wid   = tid >> 6;
    const int arowb = lane & 15;
    const int kg    = lane >> 4;

    int cols[8]; float bdv[8], gcv[8], bcv[8];
    #pragma unroll
    for (int n = 0; n < 8; ++n) {
        cols[n] = wid * 128 + n * 16 + arowb;
        bdv[n] = bd[cols[n]];
        gcv[n] = g_check[cols[n]];
        bcv[n] = b_check[cols[n]];
    }

    __syncthreads();

    bf16x8 a_hi[2][3], a_lo[2][3];
    #pragma unroll
    for (int ms = 0; ms < 2; ++ms)
        #pragma unroll
        for (int s = 0; s < 3; ++s) {
            a_hi[ms][s] = *(const bf16x8*)&Ahi[ms * 16 + arowb][s * 32 + kg * 8];
            a_lo[ms][s] = *(const bf16x8*)&Alo[ms * 16 + arowb][s * 32 + kg * 8];
        }

    f32x4 acc[2][8];
    #pragma unroll
    for (int ms = 0; ms < 2; ++ms)
        #pragma unroll
        for (int n = 0; n < 8; ++n) acc[ms][n] = (f32x4){0.f, 0.f, 0.f, 0.f};

    #pragma unroll
    for (int n = 0; n < 8; ++n) {
        #pragma unroll
        for (int s = 0; s < 3; ++s) {
            size_t off = (((size_t)(s * 512 + cols[n])) * 4 + kg) * 8;
            bf16x8 bh = *(const bf16x8*)(Bhi + off);
            bf16x8 bl = *(const bf16x8*)(Blo + off);
            acc[0][n] = __builtin_amdgcn_mfma_f32_16x16x32_bf16(a_hi[0][s], bh, acc[0][n], 0, 0, 0);
            acc[1][n] = __builtin_amdgcn_mfma_f32_16x16x32_bf16(a_hi[1][s], bh, acc[1][n], 0, 0, 0);
            acc[0][n] = __builtin_amdgcn_mfma_f32_16x16x32_bf16(a_lo[0][s], bh, acc[0][n], 0, 0, 0);
            acc[1][n] = __builtin_amdgcn_mfma_f32_16x16x32_bf16(a_lo[1][s], bh, acc[1][n], 0, 0, 0);
            acc[0][n] = __builtin_amdgcn_mfma_f32_16x16x32_bf16(a_hi[0][s], bl, acc[0][n], 0, 0, 0);
            acc[1][n] = __builtin_amdgcn_mfma_f32_16x16x32_bf16(a_hi[1][s], bl, acc[1][n], 0, 0, 0);
        }
    }

    #pragma unroll
    for (int ms = 0; ms < 2; ++ms) {
        float s1[4] = {0.f, 0.f, 0.f, 0.f};
        float s2[4] = {0.f, 0.f, 0.f, 0.f};
        #pragma unroll
        for (int n = 0; n < 8; ++n) {
            #pragma unroll
            for (int j = 0; j < 4; ++j) {
                float v = acc[ms][n][j] + bdv[n];
                acc[ms][n][j] = v;
                s1[j] += v;
                s2[j] = fmaf(v, v, s2[j]);
            }
        }
        #pragma unroll
        for (int j = 0; j < 4; ++j) {
            s1[j] = row16_sum(s1[j]);
            s2[j] = row16_sum(s2[j]);
        }
        if (arowb == 0) {
            #pragma unroll
            for (int j = 0; j < 4; ++j) {
                red[wid][ms * 16 + kg * 4 + j][0] = s1[j];
                red[wid][ms * 16 + kg * 4 + j][1] = s2[j];
            }
        }
    }
    __syncthreads();

    #pragma unroll
    for (int ms = 0; ms < 2; ++ms) {
        #pragma unroll
        for (int j = 0; j < 4; ++j) {
            const int rowl = ms * 16 + kg * 4 + j;
            float t1 = (red[0][rowl][0] + red[1][rowl][0])
                     + (red[2][rowl][0] + red[3][rowl][0]);
            float t2 = (red[0][rowl][1] + red[1][rowl][1])
                     + (red[2][rowl][1] + red[3][rowl][1]);
            float mm  = t1 * (1.f / 512.f);
            float var = t2 * (1.f / 512.f) - mm * mm;
            float iv  = rsqrtf(var + LNEPS);

            size_t R = rowbase + (size_t)rowl;
            int ii  = (int)(R & 15);
            int bb2 = (int)((R >> 4) & 31);
            int tt  = (int)(R >> 9);
            size_t orow = ((size_t)bb2 * SS + (size_t)tt * CURD + ii) * OUTD;

            #pragma unroll
            for (int n = 0; n < 8; ++n) {
                out[orow + cols[n]] =
                    (acc[ms][n][j] - mm) * iv * gcv[n] + bcv[n];
            }
        }
    }
}

// ---------------------------------------------------------------------------
extern "C" void kernel_launch(void* const* d_in, const int* in_sizes, int n_in,
                              void* d_out, int out_size, void* d_ws, size_t ws_size,
                              hipStream_t stream)
{
    const int*   x       = (const int*)  d_in[0];
    const float* emb     = (const float*)d_in[1];
    const float* Wq      = (const float*)d_in[2];
    const float* bq      = (const float*)d_in[3];
    const float* Wk      = (const float*)d_in[4];
    const float* bk      = (const float*)d_in[5];
    const float* Wv      = (const float*)d_in[6];
    const float* bv      = (const float*)d_in[7];
    const float* g_lim   = (const float*)d_in[8];
    const float* b_lim   = (const float*)d_in[9];
    const float* Ws      = (const float*)d_in[10];
    const float* bs      = (const float*)d_in[11];
    const float* g_doubt = (const float*)d_in[12];
    const float* b_doubt = (const float*)d_in[13];
    const float* Wd      = (const float*)d_in[14];
    const float* bd      = (const float*)d_in[15];
    const float* g_check = (const float*)d_in[16];
    const float* b_check = (const float*)d_in[17];

    float* out      = (float*)d_out;
    float* combined = (float*)d_ws;    // [NCH][BB][CURD][KDIM] fp32 = 40 MB
    unsigned short* whi = (unsigned short*)((char*)d_ws + WS_WHI);
    unsigned short* wlo = (unsigned short*)((char*)d_ws + WS_WLO);

    attn_kernel<<<dim3(NCH * BB / 4), dim3(256), 0, stream>>>(
        x, emb, Wq, bq, Wk, bk, Wv, bv, g_lim, b_lim, combined,
        Wd, whi, wlo);

    rec_kernel<<<dim3(BB * CURD / 2), dim3(128), 0, stream>>>(
        Ws, bs, g_doubt, b_doubt, combined);

    out_mfma_kernel<<<dim3((NCH * BB * CURD) / M_BLK), dim3(256), 0, stream>>>(
        combined, whi, wlo, bd, g_check, b_check, out);
}

// Round 7
// 463.770 us; speedup vs baseline: 1.6780x; 1.0985x over previous
//
#include <hip/hip_runtime.h>
#include <math.h>

#define VOCN 50257
#define OUTD 512
#define HIDD 64
#define CURD 16
#define BB   32
#define SS   4096
#define NCH  256      // SS / CURD
#define KDIM 80       // HIDD + CURD
#define LNEPS 1e-5f

// workspace layout
#define WS_WHI   41943040                  // combined = [0, 40MB)
#define WS_WLO   (WS_WHI + 96*512*2)

// ---------------------------------------------------------------------------
// helpers
// ---------------------------------------------------------------------------
#define DPP_ADD(x, ctrl) \
    ((x) + __int_as_float(__builtin_amdgcn_update_dpp( \
        0, __float_as_int(x), (ctrl), 0xf, 0xf, true)))

__device__ __forceinline__ float row16_sum(float x) {
    x = DPP_ADD(x, 0xB1);   // quad_perm xor1
    x = DPP_ADD(x, 0x4E);   // quad_perm xor2
    x = DPP_ADD(x, 0x141);  // row_half_mirror xor4
    x = DPP_ADD(x, 0x140);  // row_mirror xor8
    return x;
}

__device__ __forceinline__ float wave64_sum(float x) {
    float r = row16_sum(x);
    float a = __int_as_float(__builtin_amdgcn_readlane(__float_as_int(r), 0));
    float b = __int_as_float(__builtin_amdgcn_readlane(__float_as_int(r), 16));
    float c = __int_as_float(__builtin_amdgcn_readlane(__float_as_int(r), 32));
    float d = __int_as_float(__builtin_amdgcn_readlane(__float_as_int(r), 48));
    return (a + b) + (c + d);
}

__device__ __forceinline__ unsigned short f2bf(float x) {
    unsigned u = __float_as_uint(x);
    u += 0x7fffu + ((u >> 16) & 1u);
    return (unsigned short)(u >> 16);
}
__device__ __forceinline__ float bf2f(unsigned short h) {
    return __uint_as_float(((unsigned)h) << 16);
}

// branch-free gelu: 0.5h(1+erf(h/sqrt2)), erf via A&S 7.1.26 (|err|<=1.5e-7)
__device__ __forceinline__ float fast_gelu(float h) {
    float x  = h * 0.70710678118654752f;
    float xa = fabsf(x);
#if __has_builtin(__builtin_amdgcn_rcpf)
    float tq = __builtin_amdgcn_rcpf(fmaf(0.3275911f, xa, 1.0f));
#else
    float tq = 1.0f / fmaf(0.3275911f, xa, 1.0f);
#endif
    float poly = fmaf(tq, 1.061405429f, -1.453152027f);
    poly = fmaf(tq, poly, 1.421413741f);
    poly = fmaf(tq, poly, -0.284496736f);
    poly = fmaf(tq, poly, 0.254829592f);
    poly *= tq;
#if __has_builtin(__builtin_amdgcn_exp2f)
    float ex = __builtin_amdgcn_exp2f(xa * xa * -1.44269504088896f);
#else
    float ex = exp2f(xa * xa * -1.44269504088896f);
#endif
    float er = fmaf(-poly, ex, 1.0f);     // 1 - poly*exp(-x^2)
    er = copysignf(er, x);
    float hh = 0.5f * h;
    return fmaf(hh, er, hh);
}

typedef __attribute__((ext_vector_type(8))) short bf16x8;
typedef __attribute__((ext_vector_type(4))) float f32x4;

// ---------------------------------------------------------------------------
// Kernel 1: attention, ONE WAVE per (t,b) tile + Wd packing folded in.
// ---------------------------------------------------------------------------
__global__ __launch_bounds__(256) void attn_kernel(
    const int* __restrict__ x, const float* __restrict__ emb,
    const float* __restrict__ Wq, const float* __restrict__ bq,
    const float* __restrict__ Wk, const float* __restrict__ bk,
    const float* __restrict__ Wv, const float* __restrict__ bv,
    const float* __restrict__ g_lim, const float* __restrict__ b_lim,
    float* __restrict__ combined,
    const float* __restrict__ Wd,
    unsigned short* __restrict__ whi, unsigned short* __restrict__ wlo)
{
    const int wid  = threadIdx.x >> 6;
    const int lane = threadIdx.x & 63;
    const int tile = blockIdx.x * 4 + wid;
    const int t = tile >> 5, b = tile & 31;
    const int i  = lane >> 2;
    const int jg = lane & 3;
    const int j0 = jg * 4;

    __shared__ __align__(16) float ldsT[4][4][16][20];
    float (*R)[20] = ldsT[wid][0];
    float (*Q)[20] = ldsT[wid][1];
    float (*K)[20] = ldsT[wid][2];
    float (*V)[20] = ldsT[wid][3];

    int myid = 0;
    if (lane < 16) myid = x[b * SS + t * CURD + lane];
    const int id_i = __shfl(myid, i, 64);

    float4 r4 = *(const float4*)(emb + (size_t)id_i * CURD + j0);
    *(float4*)&R[i][j0] = r4;

    float rrow[16];
    {
        float4 t0 = *(const float4*)&R[i][0];
        float4 t1 = *(const float4*)&R[i][4];
        float4 t2 = *(const float4*)&R[i][8];
        float4 t3 = *(const float4*)&R[i][12];
        rrow[0]=t0.x; rrow[1]=t0.y; rrow[2]=t0.z;  rrow[3]=t0.w;
        rrow[4]=t1.x; rrow[5]=t1.y; rrow[6]=t1.z;  rrow[7]=t1.w;
        rrow[8]=t2.x; rrow[9]=t2.y; rrow[10]=t2.z; rrow[11]=t2.w;
        rrow[12]=t3.x; rrow[13]=t3.y; rrow[14]=t3.z; rrow[15]=t3.w;
    }

    float4 q4 = *(const float4*)(bq + j0);
    float4 k4 = *(const float4*)(bk + j0);
    float4 v4 = *(const float4*)(bv + j0);
    #pragma unroll
    for (int k = 0; k < 16; ++k) {
        float rv = rrow[k];
        float4 wq4 = *(const float4*)(Wq + k * CURD + j0);
        float4 wk4 = *(const float4*)(Wk + k * CURD + j0);
        float4 wv4 = *(const float4*)(Wv + k * CURD + j0);
        q4.x = fmaf(rv, wq4.x, q4.x); q4.y = fmaf(rv, wq4.y, q4.y);
        q4.z = fmaf(rv, wq4.z, q4.z); q4.w = fmaf(rv, wq4.w, q4.w);
        k4.x = fmaf(rv, wk4.x, k4.x); k4.y = fmaf(rv, wk4.y, k4.y);
        k4.z = fmaf(rv, wk4.z, k4.z); k4.w = fmaf(rv, wk4.w, k4.w);
        v4.x = fmaf(rv, wv4.x, v4.x); v4.y = fmaf(rv, wv4.y, v4.y);
        v4.z = fmaf(rv, wv4.z, v4.z); v4.w = fmaf(rv, wv4.w, v4.w);
    }
    *(float4*)&Q[i][j0] = q4;
    *(float4*)&K[i][j0] = k4;
    *(float4*)&V[i][j0] = v4;

    float qrow[16];
    {
        float4 t0 = *(const float4*)&Q[i][0];
        float4 t1 = *(const float4*)&Q[i][4];
        float4 t2 = *(const float4*)&Q[i][8];
        float4 t3 = *(const float4*)&Q[i][12];
        qrow[0]=t0.x; qrow[1]=t0.y; qrow[2]=t0.z;  qrow[3]=t0.w;
        qrow[4]=t1.x; qrow[5]=t1.y; qrow[6]=t1.z;  qrow[7]=t1.w;
        qrow[8]=t2.x; qrow[9]=t2.y; qrow[10]=t2.z; qrow[11]=t2.w;
        qrow[12]=t3.x; qrow[13]=t3.y; qrow[14]=t3.z; qrow[15]=t3.w;
    }
    float sc[4];
    #pragma unroll
    for (int jj = 0; jj < 4; ++jj) {
        const int row = j0 + jj;
        float4 c0 = *(const float4*)&K[row][0];
        float4 c1 = *(const float4*)&K[row][4];
        float4 c2 = *(const float4*)&K[row][8];
        float4 c3 = *(const float4*)&K[row][12];
        float d0 = qrow[0]*c0.x + qrow[1]*c0.y + qrow[2]*c0.z + qrow[3]*c0.w;
        float d1 = qrow[4]*c1.x + qrow[5]*c1.y + qrow[6]*c1.z + qrow[7]*c1.w;
        float d2 = qrow[8]*c2.x + qrow[9]*c2.y + qrow[10]*c2.z + qrow[11]*c2.w;
        float d3 = qrow[12]*c3.x + qrow[13]*c3.y + qrow[14]*c3.z + qrow[15]*c3.w;
        sc[jj] = ((d0 + d1) + (d2 + d3)) * 0.25f;
    }

    float mx = fmaxf(fmaxf(sc[0], sc[1]), fmaxf(sc[2], sc[3]));
    mx = fmaxf(mx, __shfl_xor(mx, 1));
    mx = fmaxf(mx, __shfl_xor(mx, 2));
    float e0 = expf(sc[0]-mx), e1 = expf(sc[1]-mx),
          e2 = expf(sc[2]-mx), e3 = expf(sc[3]-mx);
    float es = (e0 + e1) + (e2 + e3);
    es += __shfl_xor(es, 1);
    es += __shfl_xor(es, 2);
    float rs = 1.f / es;
    float4 p4 = make_float4(e0*rs, e1*rs, e2*rs, e3*rs);
    *(float4*)&R[i][j0] = p4;

    float prow[16];
    {
        float4 t0 = *(const float4*)&R[i][0];
        float4 t1 = *(const float4*)&R[i][4];
        float4 t2 = *(const float4*)&R[i][8];
        float4 t3 = *(const float4*)&R[i][12];
        prow[0]=t0.x; prow[1]=t0.y; prow[2]=t0.z;  prow[3]=t0.w;
        prow[4]=t1.x; prow[5]=t1.y; prow[6]=t1.z;  prow[7]=t1.w;
        prow[8]=t2.x; prow[9]=t2.y; prow[10]=t2.z; prow[11]=t2.w;
        prow[12]=t3.x; prow[13]=t3.y; prow[14]=t3.z; prow[15]=t3.w;
    }
    float4 w4 = make_float4(0.f, 0.f, 0.f, 0.f);
    #pragma unroll
    for (int k = 0; k < 16; ++k) {
        float4 vk = *(const float4*)&V[k][j0];
        float pv = prow[k];
        w4.x = fmaf(pv, vk.x, w4.x); w4.y = fmaf(pv, vk.y, w4.y);
        w4.z = fmaf(pv, vk.z, w4.z); w4.w = fmaf(pv, vk.w, w4.w);
    }

    float s1 = (w4.x + w4.y) + (w4.z + w4.w);
    float s2 = (w4.x*w4.x + w4.y*w4.y) + (w4.z*w4.z + w4.w*w4.w);
    s1 += __shfl_xor(s1, 1); s1 += __shfl_xor(s1, 2);
    s2 += __shfl_xor(s2, 1); s2 += __shfl_xor(s2, 2);
    float m   = s1 * (1.f / 16.f);
    float var = s2 * (1.f / 16.f) - m * m;
    float inv = rsqrtf(var + LNEPS);
    float4 gl = *(const float4*)(g_lim + j0);
    float4 bl = *(const float4*)(b_lim + j0);
    float4 o;
    o.x = (w4.x - m) * inv * gl.x + bl.x;
    o.y = (w4.y - m) * inv * gl.y + bl.y;
    o.z = (w4.z - m) * inv * gl.z + bl.z;
    o.w = (w4.w - m) * inv * gl.w + bl.w;
    *(float4*)(combined + ((size_t)tile * CURD + i) * KDIM + j0) = o;

    // fold Wd packing into the first 192 blocks
    if (blockIdx.x < 192) {
        int idx = blockIdx.x * 256 + threadIdx.x;   // 0 .. 49151 = 96*512
        int k = idx / 512, c = idx % 512;
        float v = (k < KDIM) ? Wd[(size_t)k * OUTD + c] : 0.f;
        unsigned short h = f2bf(v);
        unsigned short l = f2bf(v - bf2f(h));
        int s = k >> 5, kk = k & 31, g = kk >> 3, e = kk & 7;
        size_t o2 = (((size_t)(s * 512 + c)) * 4 + g) * 8 + e;
        whi[o2] = h;
        wlo[o2] = l;
    }
}

// ---------------------------------------------------------------------------
// Kernel 2 (rec v3): readlane all-gather — P is computed straight from the
// per-lane G register via v_readlane broadcast (no LDS round-trip on the
// critical path), and gelu is a branch-free 15-op erf approximation instead
// of ocml erff. LDS holds only the preloaded watch trajectory.
// ---------------------------------------------------------------------------
__global__ __launch_bounds__(128) void rec_kernel(
    const float* __restrict__ Ws, const float* __restrict__ bs,
    const float* __restrict__ g_doubt, const float* __restrict__ b_doubt,
    float* __restrict__ combined)
{
    __shared__ __align__(16) float s_watch[2][NCH][16];   // 32 KB

    const int wid = threadIdx.x >> 6;
    const int c   = threadIdx.x & 63;
    const int chain = blockIdx.x * 2 + wid;
    const int b = chain >> 4;
    const int r = chain & 15;

    // ---- preload this chain's full watch trajectory into LDS (wave-local) --
    {
        const int tt4 = c >> 2;             // 16 chunks per pass
        const int j4  = c & 3;              // float4 index in row
        #pragma unroll
        for (int p = 0; p < 16; ++p) {
            int t = p * 16 + tt4;
            float4 v = *(const float4*)(combined
                + ((size_t)(t * BB + b) * CURD + r) * KDIM + j4 * 4);
            *(float4*)&s_watch[wid][t][j4 * 4] = v;
        }
    }

    float Wsw[16];
    #pragma unroll
    for (int j = 0; j < 16; ++j) Wsw[j] = Ws[j * HIDD + c];

    float Wsp[64];
    float u = 0.f, w0 = 0.f;
    #pragma unroll
    for (int j = 0; j < 64; ++j) {
        float w   = Ws[(16 + j) * HIDD + c];
        float gdj = g_doubt[j];
        float bdj = b_doubt[j];
        Wsp[j] = gdj * w;
        u += Wsp[j];
        w0 = fmaf(bdj, w, w0);
    }
    const float bsc  = bs[c];
    const float gd_c = g_doubt[c];
    const float bd_c = b_doubt[c];

    size_t rowoff = ((size_t)b * CURD + r) * KDIM;
    const size_t stride = (size_t)BB * CURD * KDIM;

    // watch-part for t=0 (wave-local LDS: writes above are in-order)
    float wp0, wp1, wp2, wp3;
    {
        const float4* wrow = (const float4*)&s_watch[wid][0][0];
        float4 a0 = wrow[0], a1 = wrow[1], a2 = wrow[2], a3 = wrow[3];
        wp0 = a0.x*Wsw[0]; wp1 = a0.y*Wsw[1]; wp2 = a0.z*Wsw[2]; wp3 = a0.w*Wsw[3];
        wp0 = fmaf(a1.x, Wsw[4],  wp0); wp1 = fmaf(a1.y, Wsw[5],  wp1);
        wp2 = fmaf(a1.z, Wsw[6],  wp2); wp3 = fmaf(a1.w, Wsw[7],  wp3);
        wp0 = fmaf(a2.x, Wsw[8],  wp0); wp1 = fmaf(a2.y, Wsw[9],  wp1);
        wp2 = fmaf(a2.z, Wsw[10], wp2); wp3 = fmaf(a2.w, Wsw[11], wp3);
        wp0 = fmaf(a3.x, Wsw[12], wp0); wp1 = fmaf(a3.y, Wsw[13], wp1);
        wp2 = fmaf(a3.z, Wsw[14], wp2); wp3 = fmaf(a3.w, Wsw[15], wp3);
    }

    float P = 0.f, mp = 0.f, ip = 0.f, w0f = 0.f;
    float sv_store = 0.f;

    for (int t = 0; t < NCH; ++t) {
        // sus entering chunk t (fire-and-forget; kernel boundary = coherence)
        combined[rowoff + 16 + c] = sv_store;

        float h = (fmaf(ip, P - mp * u, bsc + w0f) + wp0)
                + ((wp1 + wp2) + wp3);

        float G = fast_gelu(h);

        // watch-part for t+1 (LDS, independent of the serial chain)
        {
            const int tn = (t + 1 < NCH) ? t + 1 : t;
            const float4* wrow = (const float4*)&s_watch[wid][tn][0];
            float4 a0 = wrow[0], a1 = wrow[1], a2 = wrow[2], a3 = wrow[3];
            wp0 = a0.x*Wsw[0]; wp1 = a0.y*Wsw[1]; wp2 = a0.z*Wsw[2]; wp3 = a0.w*Wsw[3];
            wp0 = fmaf(a1.x, Wsw[4],  wp0); wp1 = fmaf(a1.y, Wsw[5],  wp1);
            wp2 = fmaf(a1.z, Wsw[6],  wp2); wp3 = fmaf(a1.w, Wsw[7],  wp3);
            wp0 = fmaf(a2.x, Wsw[8],  wp0); wp1 = fmaf(a2.y, Wsw[9],  wp1);
            wp2 = fmaf(a2.z, Wsw[10], wp2); wp3 = fmaf(a2.w, Wsw[11], wp3);
            wp0 = fmaf(a3.x, Wsw[12], wp0); wp1 = fmaf(a3.y, Wsw[13], wp1);
            wp2 = fmaf(a3.z, Wsw[14], wp2); wp3 = fmaf(a3.w, Wsw[15], wp3);
        }

        // (m, inv) reduce — pure VALU DPP
        float s1 = wave64_sum(G);
        float s2 = wave64_sum(G * G);
        float m   = s1 * (1.f / 64.f);
        float var = s2 * (1.f / 64.f) - m * m;
        float inv = rsqrtf(var + LNEPS);

        // P = sum_j G_j * Wsp_j — G_j via v_readlane broadcast (no LDS!)
        float p0=0.f,p1=0.f,p2=0.f,p3=0.f,p4=0.f,p5=0.f,p6=0.f,p7=0.f;
        const int Gi = __float_as_int(G);
        #pragma unroll
        for (int j = 0; j < 64; j += 8) {
            float g0 = __int_as_float(__builtin_amdgcn_readlane(Gi, j + 0));
            float g1 = __int_as_float(__builtin_amdgcn_readlane(Gi, j + 1));
            float g2 = __int_as_float(__builtin_amdgcn_readlane(Gi, j + 2));
            float g3 = __int_as_float(__builtin_amdgcn_readlane(Gi, j + 3));
            float g4 = __int_as_float(__builtin_amdgcn_readlane(Gi, j + 4));
            float g5 = __int_as_float(__builtin_amdgcn_readlane(Gi, j + 5));
            float g6 = __int_as_float(__builtin_amdgcn_readlane(Gi, j + 6));
            float g7 = __int_as_float(__builtin_amdgcn_readlane(Gi, j + 7));
            p0 = fmaf(g0, Wsp[j + 0], p0);
            p1 = fmaf(g1, Wsp[j + 1], p1);
            p2 = fmaf(g2, Wsp[j + 2], p2);
            p3 = fmaf(g3, Wsp[j + 3], p3);
            p4 = fmaf(g4, Wsp[j + 4], p4);
            p5 = fmaf(g5, Wsp[j + 5], p5);
            p6 = fmaf(g6, Wsp[j + 6], p6);
            p7 = fmaf(g7, Wsp[j + 7], p7);
        }
        P = ((p0 + p1) + (p2 + p3)) + ((p4 + p5) + (p6 + p7));

        sv_store = fmaf((G - m) * inv, gd_c, bd_c);
        mp = m; ip = inv; w0f = w0;
        rowoff += stride;
    }
}

// ---------------------------------------------------------------------------
// Kernel 3: out = LN(combined @ Wd + bd) * g_check + b_check  (split-bf16
// MFMA; proven R1 version).
// ---------------------------------------------------------------------------
#define M_BLK 32
__global__ __launch_bounds__(256) void out_mfma_kernel(
    const float* __restrict__ combined,
    const unsigned short* __restrict__ Bhi,
    const unsigned short* __restrict__ Blo,
    const float* __restrict__ bd, const float* __restrict__ g_check,
    const float* __restrict__ b_check, float* __restrict__ out)
{
    __shared__ __align__(16) unsigned short Ahi[M_BLK][104];
    __shared__ __align__(16) unsigned short Alo[M_BLK][104];
    __shared__ float red[4][M_BLK][2];

    const int tid = threadIdx.x;
    const size_t rowbase = (size_t)blockIdx.x * M_BLK;

    {
        const float4* src4 = (const float4*)(combined + rowbase * KDIM);
        #pragma unroll
        for (int u2 = 0; u2 < 3; ++u2) {
            int idx = tid + 256 * u2;
            if (idx < M_BLK * 20) {
                float4 v = src4[idx];
                int rr = idx / 20, k4 = idx % 20;
                float vs[4] = {v.x, v.y, v.z, v.w};
                #pragma unroll
                for (int e = 0; e < 4; ++e) {
                    unsigned short h = f2bf(vs[e]);
                    Ahi[rr][k4 * 4 + e] = h;
                    Alo[rr][k4 * 4 + e] = f2bf(vs[e] - bf2f(h));
                }
            }
        }
        #pragma unroll
        for (int u2 = 0; u2 < 2; ++u2) {
            int idx = tid + 256 * u2;
            int rr = idx >> 4, kk = 80 + (idx & 15);
            Ahi[rr][kk] = 0;
            Alo[rr][kk] = 0;
        }
    }

    const int lane  = tid & 63;
    const int wid   = tid >> 6;
    const int arowb = lane & 15;
    const int kg    = lane >> 4;

    int cols[8]; float bdv[8], gcv[8], bcv[8];
    #pragma unroll
    for (int n = 0; n < 8; ++n) {
        cols[n] = wid * 128 + n * 16 + arowb;
        bdv[n] = bd[cols[n]];
        gcv[n] = g_check[cols[n]];
        bcv[n] = b_check[cols[n]];
    }

    __syncthreads();

    bf16x8 a_hi[2][3], a_lo[2][3];
    #pragma unroll
    for (int ms = 0; ms < 2; ++ms)
        #pragma unroll
        for (int s = 0; s < 3; ++s) {
            a_hi[ms][s] = *(const bf16x8*)&Ahi[ms * 16 + arowb][s * 32 + kg * 8];
            a_lo[ms][s] = *(const bf16x8*)&Alo[ms * 16 + arowb][s * 32 + kg * 8];
        }

    f32x4 acc[2][8];
    #pragma unroll
    for (int ms = 0; ms < 2; ++ms)
        #pragma unroll
        for (int n = 0; n < 8; ++n) acc[ms][n] = (f32x4){0.f, 0.f, 0.f, 0.f};

    #pragma unroll
    for (int n = 0; n < 8; ++n) {
        #pragma unroll
        for (int s = 0; s < 3; ++s) {
            size_t off = (((size_t)(s * 512 + cols[n])) * 4 + kg) * 8;
            bf16x8 bh = *(const bf16x8*)(Bhi + off);
            bf16x8 bl = *(const bf16x8*)(Blo + off);
            acc[0][n] = __builtin_amdgcn_mfma_f32_16x16x32_bf16(a_hi[0][s], bh, acc[0][n], 0, 0, 0);
            acc[1][n] = __builtin_amdgcn_mfma_f32_16x16x32_bf16(a_hi[1][s], bh, acc[1][n], 0, 0, 0);
            acc[0][n] = __builtin_amdgcn_mfma_f32_16x16x32_bf16(a_lo[0][s], bh, acc[0][n], 0, 0, 0);
            acc[1][n] = __builtin_amdgcn_mfma_f32_16x16x32_bf16(a_lo[1][s], bh, acc[1][n], 0, 0, 0);
            acc[0][n] = __builtin_amdgcn_mfma_f32_16x16x32_bf16(a_hi[0][s], bl, acc[0][n], 0, 0, 0);
            acc[1][n] = __builtin_amdgcn_mfma_f32_16x16x32_bf16(a_hi[1][s], bl, acc[1][n], 0, 0, 0);
        }
    }

    #pragma unroll
    for (int ms = 0; ms < 2; ++ms) {
        float s1[4] = {0.f, 0.f, 0.f, 0.f};
        float s2[4] = {0.f, 0.f, 0.f, 0.f};
        #pragma unroll
        for (int n = 0; n < 8; ++n) {
            #pragma unroll
            for (int j = 0; j < 4; ++j) {
                float v = acc[ms][n][j] + bdv[n];
                acc[ms][n][j] = v;
                s1[j] += v;
                s2[j] = fmaf(v, v, s2[j]);
            }
        }
        #pragma unroll
        for (int j = 0; j < 4; ++j) {
            s1[j] = row16_sum(s1[j]);
            s2[j] = row16_sum(s2[j]);
        }
        if (arowb == 0) {
            #pragma unroll
            for (int j = 0; j < 4; ++j) {
                red[wid][ms * 16 + kg * 4 + j][0] = s1[j];
                red[wid][ms * 16 + kg * 4 + j][1] = s2[j];
            }
        }
    }
    __syncthreads();

    #pragma unroll
    for (int ms = 0; ms < 2; ++ms) {
        #pragma unroll
        for (int j = 0; j < 4; ++j) {
            const int rowl = ms * 16 + kg * 4 + j;
            float t1 = (red[0][rowl][0] + red[1][rowl][0])
                     + (red[2][rowl][0] + red[3][rowl][0]);
            float t2 = (red[0][rowl][1] + red[1][rowl][1])
                     + (red[2][rowl][1] + red[3][rowl][1]);
            float mm  = t1 * (1.f / 512.f);
            float var = t2 * (1.f / 512.f) - mm * mm;
            float iv  = rsqrtf(var + LNEPS);

            size_t R = rowbase + (size_t)rowl;
            int ii  = (int)(R & 15);
            int bb2 = (int)((R >> 4) & 31);
            int tt  = (int)(R >> 9);
            size_t orow = ((size_t)bb2 * SS + (size_t)tt * CURD + ii) * OUTD;

            #pragma unroll
            for (int n = 0; n < 8; ++n) {
                out[orow + cols[n]] =
                    (acc[ms][n][j] - mm) * iv * gcv[n] + bcv[n];
            }
        }
    }
}

// ---------------------------------------------------------------------------
extern "C" void kernel_launch(void* const* d_in, const int* in_sizes, int n_in,
                              void* d_out, int out_size, void* d_ws, size_t ws_size,
                              hipStream_t stream)
{
    const int*   x       = (const int*)  d_in[0];
    const float* emb     = (const float*)d_in[1];
    const float* Wq      = (const float*)d_in[2];
    const float* bq      = (const float*)d_in[3];
    const float* Wk      = (const float*)d_in[4];
    const float* bk      = (const float*)d_in[5];
    const float* Wv      = (const float*)d_in[6];
    const float* bv      = (const float*)d_in[7];
    const float* g_lim   = (const float*)d_in[8];
    const float* b_lim   = (const float*)d_in[9];
    const float* Ws      = (const float*)d_in[10];
    const float* bs      = (const float*)d_in[11];
    const float* g_doubt = (const float*)d_in[12];
    const float* b_doubt = (const float*)d_in[13];
    const float* Wd      = (const float*)d_in[14];
    const float* bd      = (const float*)d_in[15];
    const float* g_check = (const float*)d_in[16];
    const float* b_check = (const float*)d_in[17];

    float* out      = (float*)d_out;
    float* combined = (float*)d_ws;    // [NCH][BB][CURD][KDIM] fp32 = 40 MB
    unsigned short* whi = (unsigned short*)((char*)d_ws + WS_WHI);
    unsigned short* wlo = (unsigned short*)((char*)d_ws + WS_WLO);

    attn_kernel<<<dim3(NCH * BB / 4), dim3(256), 0, stream>>>(
        x, emb, Wq, bq, Wk, bk, Wv, bv, g_lim, b_lim, combined,
        Wd, whi, wlo);

    rec_kernel<<<dim3(BB * CURD / 2), dim3(128), 0, stream>>>(
        Ws, bs, g_doubt, b_doubt, combined);

    out_mfma_kernel<<<dim3((NCH * BB * CURD) / M_BLK), dim3(256), 0, stream>>>(
        combined, whi, wlo, bd, g_check, b_check, out);
}